// Round 14
// baseline (282.717 us; speedup 1.0000x reference)
//
#include <hip/hip_runtime.h>
#include <stdint.h>

typedef unsigned short u16;
typedef __attribute__((ext_vector_type(8))) short short8;
typedef __attribute__((ext_vector_type(4))) short short4v;
typedef __attribute__((ext_vector_type(4))) float floatx4;

#define S_LEN 2048
#define NQKV 3072

#if __has_builtin(__builtin_amdgcn_exp2f)
#define EXP2F __builtin_amdgcn_exp2f
#else
#define EXP2F exp2f
#endif

__device__ inline float bf2f(u16 u) {
  union { uint32_t u; float f; } v; v.u = ((uint32_t)u) << 16; return v.f;
}
__device__ inline u16 f2bf(float f) {
  union { float f; uint32_t u; } v; v.f = f;
  uint32_t r = v.u + 0x7fffu + ((v.u >> 16) & 1u);
  return (u16)(r >> 16);
}
__device__ inline void gl2lds16(const u16* g, u16* l) {
  __builtin_amdgcn_global_load_lds((const __attribute__((address_space(1))) uint32_t*)g,
                                   (__attribute__((address_space(3))) uint32_t*)l, 16, 0, 0);
}

// ---------------- fused prep: x cast + 4 weight transposes + RoPE table ----------------
__global__ void prep_k(const float* __restrict__ x, u16* __restrict__ Xb,
                       const float* __restrict__ Wq, const float* __restrict__ Wk,
                       const float* __restrict__ Wv, const float* __restrict__ Wo,
                       u16* __restrict__ WT, u16* __restrict__ WoT,
                       const int* __restrict__ pos, float2* __restrict__ rtab) {
  __shared__ u16 tile[32][33];
  const int b = blockIdx.x, t = threadIdx.x;
  if (b < 8192) {  // cast
    int i = b * 256 + t;
    float4 v = ((const float4*)x)[i];
    ushort4 o;
    o.x = f2bf(v.x); o.y = f2bf(v.y); o.z = f2bf(v.z); o.w = f2bf(v.w);
    ((ushort4*)Xb)[i] = o;
    return;
  }
  if (b >= 18432) {  // RoPE table
    int i = (b - 18432) * 256 + t;  // 0..131071
    int s = i >> 6, d = i & 63;
    float freq = __expf(-(float)d * 0.015625f * 9.210340371976184f);
    float ang = (float)pos[s] * freq;
    rtab[i] = make_float2(cosf(ang), sinf(ang));
    return;
  }
  int wb = b - 8192;
  const float* src; u16* dst; int bx, by;
  if (wb < 4096)      { src = Wq; dst = WT;                       bx = wb & 63;  by = wb >> 6; }
  else if (wb < 5120) { src = Wk; dst = WT + (size_t)2048 * 2048; bx = (wb - 4096) & 15; by = (wb - 4096) >> 4; }
  else if (wb < 6144) { src = Wv; dst = WT + (size_t)2560 * 2048; bx = (wb - 5120) & 15; by = (wb - 5120) >> 4; }
  else                { src = Wo; dst = WoT;                      bx = (wb - 6144) & 63; by = (wb - 6144) >> 6; }
  const int N = (wb >= 4096 && wb < 6144) ? 512 : 2048;
  int n0 = bx * 32, k0 = by * 32;
  int tx = t & 31, ty = t >> 5;  // 32 x 8
#pragma unroll
  for (int i = 0; i < 4; i++)
    tile[ty + 8 * i][tx] = f2bf(src[(size_t)(k0 + ty + 8 * i) * N + n0 + tx]);
  __syncthreads();
#pragma unroll
  for (int i = 0; i < 4; i++)
    dst[(size_t)(n0 + ty + 8 * i) * 2048 + k0 + tx] = tile[tx][ty + 8 * i];
}

// ---------------- GEMM 128x128, fp32 out (Wo projection) — unchanged from R13 ----------------
__global__ __launch_bounds__(256) void gemm128_k(const u16* __restrict__ A,
                                                 const u16* __restrict__ Bt,
                                                 float* __restrict__ C, int M, int N, int K) {
  __shared__ u16 Al[2][8192];  // [buf][128 rows][64 cols u16], slot-swizzled
  __shared__ u16 Bl[2][8192];
  const int TN = N >> 7;
  int flat = blockIdx.x;
  const int cpx = gridDim.x >> 3;
  flat = (flat & 7) * cpx + (flat >> 3);
  const int m0 = (flat / TN) << 7, n0 = (flat % TN) << 7;
  const int t = threadIdx.x, w = t >> 6, lane = t & 63;
  const int quad = lane >> 4, l16 = lane & 15;
  const int wm = w >> 1, wn = w & 1;
  const int sr = t >> 3, sl = t & 7;  // staging: row-in-round (32/round), 16B slot
  floatx4 acc[4][4] = {};
  const int NKT = K >> 6;
  const int ra_l = wm * 64 + l16;
  const int rb_l = wn * 64 + l16;

  // prologue: stage kt0 -> buf0, full drain once
#pragma unroll
  for (int round = 0; round < 4; round++) {
    int r = round * 32 + sr;
    int so = (sl ^ (r & 7)) << 3;
    gl2lds16(A + (size_t)(m0 + r) * K + so, &Al[0][0] + round * 2048 + t * 8);
    gl2lds16(Bt + (size_t)(n0 + r) * K + so, &Bl[0][0] + round * 2048 + t * 8);
  }
  asm volatile("s_waitcnt vmcnt(0)" ::: "memory");
  __builtin_amdgcn_s_barrier();

  for (int kt = 0; kt < NKT; kt++) {
    const int cur = kt & 1;
    __builtin_amdgcn_s_barrier();  // WAR: all waves done reading buf[cur^1]
    if (kt + 1 < NKT) {            // prefetch kt+1 into the other buffer
      const int k1 = (kt + 1) << 6;
#pragma unroll
      for (int round = 0; round < 4; round++) {
        int r = round * 32 + sr;
        int so = (sl ^ (r & 7)) << 3;
        gl2lds16(A + (size_t)(m0 + r) * K + k1 + so, &Al[cur ^ 1][0] + round * 2048 + t * 8);
        gl2lds16(Bt + (size_t)(n0 + r) * K + k1 + so, &Bl[cur ^ 1][0] + round * 2048 + t * 8);
      }
      asm volatile("s_waitcnt vmcnt(8)" ::: "memory");  // retires buf[cur]'s 8 loads
    } else {
      asm volatile("s_waitcnt vmcnt(0)" ::: "memory");
    }
    __builtin_amdgcn_s_barrier();  // RAW: buf[cur] landed
    const u16* Ab = &Al[cur][0];
    const u16* Bb = &Bl[cur][0];
    short8 af[4][2], bf[4][2];
#pragma unroll
    for (int mt = 0; mt < 4; mt++) {
      int ra = ra_l + mt * 16;
      const u16* base = Ab + ra * 64;
#pragma unroll
      for (int ks = 0; ks < 2; ks++)
        af[mt][ks] = *(const short8*)(base + (((ks * 4 + quad) ^ (ra & 7)) << 3));
    }
#pragma unroll
    for (int nt = 0; nt < 4; nt++) {
      int rb = rb_l + nt * 16;
      const u16* base = Bb + rb * 64;
#pragma unroll
      for (int ks = 0; ks < 2; ks++)
        bf[nt][ks] = *(const short8*)(base + (((ks * 4 + quad) ^ (rb & 7)) << 3));
    }
    __builtin_amdgcn_s_setprio(1);
#pragma unroll
    for (int mt = 0; mt < 4; mt++)
#pragma unroll
      for (int nt = 0; nt < 4; nt++)
#pragma unroll
        for (int ks = 0; ks < 2; ks++)
          acc[mt][nt] = __builtin_amdgcn_mfma_f32_16x16x32_bf16(af[mt][ks], bf[nt][ks], acc[mt][nt], 0, 0, 0);
    __builtin_amdgcn_s_setprio(0);
  }
  // epilogue: fp32 write
#pragma unroll
  for (int mt = 0; mt < 4; mt++)
#pragma unroll
    for (int nt = 0; nt < 4; nt++)
#pragma unroll
      for (int r = 0; r < 4; r++) {
        int row = m0 + wm * 64 + mt * 16 + quad * 4 + r;
        int col = n0 + wn * 64 + nt * 16 + l16;
        C[(size_t)row * N + col] = acc[mt][nt][r];
      }
}

// ---------------- GEMM 128x128 QKV variant (R14): RoPE + V-repack epilogues ----------------
// Same verified K-loop as gemm128_k (BK=64, slot-XOR swizzle, counted vmcnt(8)
// double-buffer, setprio). Grid 32x24 = 768 blocks = 3 blocks/CU (100% machine,
// 3 independent barrier groups/CU) vs gemm256's 192 blocks (75%, 1 group/CU).
// Column remap: col(nt) = n0 + (nt>>1)*64 + wn*32 + (nt&1)*16 + l16 -> the
// RoPE pair (d, d+64) lives in (acc[mt][nt], acc[mt][nt+2]), nt in {0,1}.
// Pure relabeling (same dot products, same k-order as gemm256: both BK=64,
// ks-order identical) -> bit-identical pre-rope values; rb&7 = l16&7 keeps the
// bank-conflict-free swizzle property.
// Epilogues (ported from gemm256, mapping unchanged so attn needs no change):
//  - Q/K tiles (n0 < 2560): RoPE from rtab on unrounded f32, bf16 write.
//  - V tiles (n0 >= 2560, one kvh each): transpose 128x128 acc through the
//    idle 64KB LDS (XOR swizzle row^((col&15)<<3)), store repacked to
//    (X,Y) = (kvh*512 + d*4 + key>>9, key&511). m0loc>>9 constant per tile;
//    Y never wraps; tiles disjoint. s_barrier separates the K-loop's last
//    ds_reads (all consumed before it) from the scatter.
__global__ __launch_bounds__(256) void gemmqkv_k(const u16* __restrict__ A,
                                                 const u16* __restrict__ Bt,
                                                 u16* __restrict__ C,
                                                 const float2* __restrict__ rtab,
                                                 int N, int K) {
  __shared__ u16 Al[2][8192];
  __shared__ u16 Bl[2][8192];
  const int TN = N >> 7;  // 24
  int flat = blockIdx.x;
  const int cpx = gridDim.x >> 3;
  flat = (flat & 7) * cpx + (flat >> 3);
  const int m0 = (flat / TN) << 7, n0 = (flat % TN) << 7;
  const int t = threadIdx.x, w = t >> 6, lane = t & 63;
  const int quad = lane >> 4, l16 = lane & 15;
  const int wm = w >> 1, wn = w & 1;
  const int sr = t >> 3, sl = t & 7;
  floatx4 acc[4][4] = {};
  const int NKT = K >> 6;
  const int ra_l = wm * 64 + l16;

  // prologue: stage kt0 -> buf0, full drain once
#pragma unroll
  for (int round = 0; round < 4; round++) {
    int r = round * 32 + sr;
    int so = (sl ^ (r & 7)) << 3;
    gl2lds16(A + (size_t)(m0 + r) * K + so, &Al[0][0] + round * 2048 + t * 8);
    gl2lds16(Bt + (size_t)(n0 + r) * K + so, &Bl[0][0] + round * 2048 + t * 8);
  }
  asm volatile("s_waitcnt vmcnt(0)" ::: "memory");
  __builtin_amdgcn_s_barrier();

  for (int kt = 0; kt < NKT; kt++) {
    const int cur = kt & 1;
    __builtin_amdgcn_s_barrier();  // WAR
    if (kt + 1 < NKT) {
      const int k1 = (kt + 1) << 6;
#pragma unroll
      for (int round = 0; round < 4; round++) {
        int r = round * 32 + sr;
        int so = (sl ^ (r & 7)) << 3;
        gl2lds16(A + (size_t)(m0 + r) * K + k1 + so, &Al[cur ^ 1][0] + round * 2048 + t * 8);
        gl2lds16(Bt + (size_t)(n0 + r) * K + k1 + so, &Bl[cur ^ 1][0] + round * 2048 + t * 8);
      }
      asm volatile("s_waitcnt vmcnt(8)" ::: "memory");
    } else {
      asm volatile("s_waitcnt vmcnt(0)" ::: "memory");
    }
    __builtin_amdgcn_s_barrier();  // RAW
    const u16* Ab = &Al[cur][0];
    const u16* Bb = &Bl[cur][0];
    short8 af[4][2], bf[4][2];
#pragma unroll
    for (int mt = 0; mt < 4; mt++) {
      int ra = ra_l + mt * 16;
      const u16* base = Ab + ra * 64;
#pragma unroll
      for (int ks = 0; ks < 2; ks++)
        af[mt][ks] = *(const short8*)(base + (((ks * 4 + quad) ^ (ra & 7)) << 3));
    }
#pragma unroll
    for (int nt = 0; nt < 4; nt++) {
      int rb = ((nt >> 1) << 6) + wn * 32 + ((nt & 1) << 4) + l16;  // RoPE-pair remap
      const u16* base = Bb + rb * 64;
#pragma unroll
      for (int ks = 0; ks < 2; ks++)
        bf[nt][ks] = *(const short8*)(base + (((ks * 4 + quad) ^ (rb & 7)) << 3));
    }
    __builtin_amdgcn_s_setprio(1);
#pragma unroll
    for (int mt = 0; mt < 4; mt++)
#pragma unroll
      for (int nt = 0; nt < 4; nt++)
#pragma unroll
        for (int ks = 0; ks < 2; ks++)
          acc[mt][nt] = __builtin_amdgcn_mfma_f32_16x16x32_bf16(af[mt][ks], bf[nt][ks], acc[mt][nt], 0, 0, 0);
    __builtin_amdgcn_s_setprio(0);
  }

  if (n0 < 2560) {
    // ---- RoPE epilogue (Q/K tiles): pairs (acc[mt][nt], acc[mt][nt+2]) ----
#pragma unroll
    for (int mt = 0; mt < 4; mt++)
#pragma unroll
      for (int r = 0; r < 4; r++) {
        int row = m0 + wm * 64 + mt * 16 + quad * 4 + r;
        int ri = (row & (S_LEN - 1)) * 64;
#pragma unroll
        for (int nt = 0; nt < 2; nt++) {
          int d = wn * 32 + nt * 16 + l16;
          float2 cs = rtab[ri + d];
          float a0 = acc[mt][nt][r], a1 = acc[mt][nt + 2][r];
          C[(size_t)row * N + n0 + d]      = f2bf(a0 * cs.x - a1 * cs.y);
          C[(size_t)row * N + n0 + d + 64] = f2bf(a1 * cs.x + a0 * cs.y);
        }
      }
  } else {
    // ---- V epilogue: transpose 128x128 through LDS, repack into QKV V stripe ----
    const int bbv = m0 >> 11, m0loc = m0 & 2047;
    const int kvh = (n0 - 2560) >> 7;
    u16* SM = &Al[0][0];  // 32 KiB
    __builtin_amdgcn_s_barrier();  // all waves' last-tile ds_reads consumed
#pragma unroll
    for (int mt = 0; mt < 4; mt++)
#pragma unroll
      for (int nt = 0; nt < 4; nt++) {
        int lrow = wm * 64 + mt * 16 + quad * 4;
        int lcol = ((nt >> 1) << 6) + wn * 32 + ((nt & 1) << 4) + l16;
        short4v v4 = { (short)f2bf(acc[mt][nt][0]),
                       (short)f2bf(acc[mt][nt][1]),
                       (short)f2bf(acc[mt][nt][2]),
                       (short)f2bf(acc[mt][nt][3]) };
        *(short4v*)(SM + lcol * 128 + (lrow ^ ((lcol & 15) << 3))) = v4;
      }
    asm volatile("s_waitcnt lgkmcnt(0)" ::: "memory");
    __builtin_amdgcn_s_barrier();
    // gather rows of V^T (contiguous keys) -> coalesced global stores
#pragma unroll
    for (int it = 0; it < 8; it++) {
      int u = it * 256 + t;
      int key0 = (u & 15) * 8, lcol = u >> 4;  // lcol = d in [0,128)
      short8 v = *(const short8*)(SM + lcol * 128 + (key0 ^ ((lcol & 15) << 3)));
      int X = kvh * 512 + lcol * 4 + (m0loc >> 9);
      int Y = 2560 + (m0loc & 511) + key0;
      *(short8*)(C + (size_t)(bbv * 2048 + X) * N + Y) = v;
    }
  }
}

// ---------------- Flash attention, causal GQA (unchanged from R12/R13) ----------------
__global__ __launch_bounds__(256) void attn_k(const u16* __restrict__ qkv,
                                              u16* __restrict__ ctx) {
  __shared__ u16 Kl[2][64 * 128];      // 2 x 16384 B, [pos][d] swizzled, rows kperm'd
  __shared__ u16 Vl[2][128 * 64];      // 2 x 16384 B, [d][key] swizzled
  const int f = blockIdx.x;
  const int p = f >> 5;
  const int hb = f & 31;
  const int h = hb & 15, bb = hb >> 4;
  const int kvh = h >> 2;
  const int t = threadIdx.x, w = t >> 6, lane = t & 63;
  const int quad = lane >> 4, l16 = lane & 15;
  const int sx = l16 & 7;              // read-side swizzle key
  const int kslot = lane & 15;
  const int vd0 = w * 32 + (lane >> 3);
  const int vslot = lane & 7;
  const int grow0 = (w & 1) * 4 + (w >> 1) * 32 + quad;
  const size_t rowbase = (size_t)bb * S_LEN;
  const u16* Kg0 = qkv + rowbase * NQKV + 2048 + kvh * 128;
  const u16* Vg0 = qkv + (rowbase + kvh * 512) * NQKV + 2560;  // repacked V stripe base
  const float c2 = 0.12751744f;  // (1/sqrt(128)) * log2(e)
  short8 onesf = {16256, 16256, 16256, 16256, 16256, 16256, 16256, 16256};  // bf16 1.0 x8

  for (int phase = 0; phase < 2; phase++) {
    const int qt = phase ? p : 31 - p;  // q-tile index; qt+1 k-iters
    const int rw = qt * 64 + w * 16;    // this wave's first q-row
    const int qrow = rw + l16;          // this lane's q-row (swapped layout: col=q)

    short8 qf[4];
#pragma unroll
    for (int ks = 0; ks < 4; ks++)
      qf[ks] = *(const short8*)(qkv + (rowbase + rw + l16) * NQKV + h * 128 + ks * 32 + quad * 8);

    floatx4 acc[8] = {};
    floatx4 accl = {0.f, 0.f, 0.f, 0.f};

    __syncthreads();  // cross-phase WAR: protect buf0 from previous phase's reads
    // prologue DMA: kb=0 -> buffer 0
    {
#pragma unroll
      for (int ii = 0; ii < 4; ii++) {
        int p7 = (quad + 4 * ii) & 7;  // (position)&7 for the slot swizzle
        int grow = grow0 + 8 * ii;     // permuted global key row
        gl2lds16(Kg0 + (size_t)grow * NQKV + ((kslot ^ p7) * 8),
                 &Kl[0][0] + w * 2048 + ii * 512 + lane * 8);
      }
#pragma unroll
      for (int ii = 0; ii < 4; ii++) {
        int d = vd0 + ii * 8;
        int s8 = (vslot ^ (d & 7)) * 8;
        gl2lds16(Vg0 + (size_t)(d * 4) * NQKV + s8,  // kb=0
                 &Vl[0][0] + w * 2048 + ii * 512 + lane * 8);
      }
    }

    for (int kb = 0; kb <= qt; kb++) {
      const int cur = kb & 1;
      __builtin_amdgcn_s_barrier();  // WAR: all waves done reading buf[cur^1]
      if (kb < qt) {    // prefetch kb+1 into the other buffer
        const int kn = kb + 1;
        const u16* Kg = Kg0 + (size_t)kn * 64 * NQKV;
        u16* KlN = &Kl[cur ^ 1][0];
        u16* VlN = &Vl[cur ^ 1][0];
#pragma unroll
        for (int ii = 0; ii < 4; ii++) {
          int p7 = (quad + 4 * ii) & 7;
          int grow = grow0 + 8 * ii;
          gl2lds16(Kg + (size_t)grow * NQKV + ((kslot ^ p7) * 8),
                   KlN + w * 2048 + ii * 512 + lane * 8);
        }
#pragma unroll
        for (int ii = 0; ii < 4; ii++) {
          int d = vd0 + ii * 8;
          int s8 = (vslot ^ (d & 7)) * 8;
          gl2lds16(Vg0 + (size_t)(d * 4 + (kn >> 3)) * NQKV + (kn & 7) * 64 + s8,
                   VlN + w * 2048 + ii * 512 + lane * 8);
        }
        asm volatile("s_waitcnt vmcnt(8)" ::: "memory");  // buf[cur]'s 8 loads done
      } else {
        asm volatile("s_waitcnt vmcnt(0)" ::: "memory");  // last iter: full drain
      }
      __builtin_amdgcn_s_barrier();  // RAW: all waves' buf[cur] loads landed
      const u16* KlB = &Kl[cur][0];
      const u16* VlB = &Vl[cur][0];

      // ---- QK^T (swapped: A=K, B=Q -> lane holds S[pos=quad*4+r][q=l16]) ----
      floatx4 sc[4];
      __builtin_amdgcn_s_setprio(1);
#pragma unroll
      for (int nt = 0; nt < 4; nt++) {
        const u16* Krow = KlB + (nt * 16 + l16) * 128;
        short8 kf[4];
#pragma unroll
        for (int ks = 0; ks < 4; ks++)
          kf[ks] = *(const short8*)(Krow + (((ks * 4 + quad) ^ sx) * 8));
        floatx4 s = {0.f, 0.f, 0.f, 0.f};
#pragma unroll
        for (int ks = 0; ks < 4; ks++) s = __builtin_amdgcn_mfma_f32_16x16x32_bf16(kf[ks], qf[ks], s, 0, 0, 0);
        sc[nt] = s;
      }
      __builtin_amdgcn_s_setprio(0);
      // ---- P = exp2(score*c2), causal mask, trunc-pack DIRECTLY into A-frags ----
      const bool diag = (kb == qt);
      uint32_t pw[8];
#pragma unroll
      for (int nt = 0; nt < 4; nt++) {
        uint32_t w0 = 0, w1 = 0;
#pragma unroll
        for (int r = 0; r < 4; r++) {
          float e = EXP2F(sc[nt][r] * c2);
          if (diag) {
            int keyg = kb * 64 + quad * 8 + (nt & 1) * 4 + (nt >> 1) * 32 + r;
            if (keyg > qrow) e = 0.f;
          }
          uint32_t b = __float_as_uint(e) >> 16;
          if (r == 0) w0 = b;
          else if (r == 1) w0 |= b << 16;
          else if (r == 2) w1 = b;
          else w1 |= b << 16;
        }
        pw[nt * 2] = w0;
        pw[nt * 2 + 1] = w1;
      }
      union { short8 v; uint32_t u[4]; } pu0, pu1;
      pu0.u[0] = pw[0]; pu0.u[1] = pw[1]; pu0.u[2] = pw[2]; pu0.u[3] = pw[3];
      pu1.u[0] = pw[4]; pu1.u[1] = pw[5]; pu1.u[2] = pw[6]; pu1.u[3] = pw[7];
      const short8 pf0 = pu0.v, pf1 = pu1.v;  // PV A-frags, keys 0-31 / 32-63

      // ---- PV (+ ones-column row-sum into accl) ----
      __builtin_amdgcn_s_setprio(1);
      accl = __builtin_amdgcn_mfma_f32_16x16x32_bf16(pf0, onesf, accl, 0, 0, 0);
      accl = __builtin_amdgcn_mfma_f32_16x16x32_bf16(pf1, onesf, accl, 0, 0, 0);
#pragma unroll
      for (int nto = 0; nto < 8; nto++) {
        const u16* Vrow = VlB + (nto * 16 + l16) * 64;
        short8 vf0 = *(const short8*)(Vrow + ((quad ^ sx) * 8));
        short8 vf1 = *(const short8*)(Vrow + (((quad + 4) ^ sx) * 8));
        acc[nto] = __builtin_amdgcn_mfma_f32_16x16x32_bf16(pf0, vf0, acc[nto], 0, 0, 0);
        acc[nto] = __builtin_amdgcn_mfma_f32_16x16x32_bf16(pf1, vf1, acc[nto], 0, 0, 0);
      }
      __builtin_amdgcn_s_setprio(0);
    }
    // ---- epilogue for this q-tile (lane holds O[q=quad*4+r][d=l16]) ----
#pragma unroll
    for (int r = 0; r < 4; r++) {
      float inv = 1.0f / accl[r];
      int rowg = rw + quad * 4 + r;
#pragma unroll
      for (int nto = 0; nto < 8; nto++) {
        int col = h * 128 + nto * 16 + l16;
        ctx[(rowbase + rowg) * 2048 + col] = f2bf(acc[nto][r] * inv);
      }
    }
  }
}

extern "C" void kernel_launch(void* const* d_in, const int* in_sizes, int n_in,
                              void* d_out, int out_size, void* d_ws, size_t ws_size,
                              hipStream_t stream) {
  const float* x  = (const float*)d_in[0];
  const int* pos  = (const int*)d_in[1];
  const float* Wq = (const float*)d_in[2];
  const float* Wk = (const float*)d_in[3];
  const float* Wv = (const float*)d_in[4];
  const float* Wo = (const float*)d_in[5];
  float* out = (float*)d_out;
  char* ws = (char*)d_ws;
  // ws layout (bf16): Xb[4096][2048] | WT[3072][2048] | WoT[2048][2048] | QKV[4096][3072] | CTX[4096][2048]
  u16* Xb  = (u16*)(ws);
  u16* WT  = (u16*)(ws + 16777216);
  u16* WoT = (u16*)(ws + 29360128);
  u16* QKV = (u16*)(ws + 37748736);
  u16* CTX = (u16*)(ws + 62914560);
  // rtab aliases CTX start (1 MB): written by prep_k, read by gemmqkv_k,
  // then CTX is overwritten by attn_k (stream-ordered, safe).
  float2* rtab = (float2*)(ws + 62914560);

  // prep: 8192 cast + 10240 transpose + 512 rtab blocks
  hipLaunchKernelGGL(prep_k, dim3(18944), dim3(256), 0, stream, x, Xb, Wq, Wk, Wv, Wo, WT, WoT, pos, rtab);

  // QKV projection + fused RoPE + fused V-repack: 4096x3072x2048, grid 768 (768%8==0)
  hipLaunchKernelGGL(gemmqkv_k, dim3(768), dim3(256), 0, stream, Xb, WT, QKV, rtab, 3072, 2048);
  hipLaunchKernelGGL(attn_k, dim3(512), dim3(256), 0, stream, QKV, CTX);
  // Wo projection: 4096x2048x2048, grid 512 (512%8==0)
  hipLaunchKernelGGL(gemm128_k, dim3(512), dim3(256), 0, stream, CTX, WoT, out, 4096, 2048, 2048);
}

// Round 15
// 269.453 us; speedup vs baseline: 1.0492x; 1.0492x over previous
//
#include <hip/hip_runtime.h>
#include <stdint.h>

typedef unsigned short u16;
typedef __attribute__((ext_vector_type(8))) short short8;
typedef __attribute__((ext_vector_type(4))) short short4v;
typedef __attribute__((ext_vector_type(4))) float floatx4;

#define S_LEN 2048
#define NQKV 3072

#if __has_builtin(__builtin_amdgcn_exp2f)
#define EXP2F __builtin_amdgcn_exp2f
#else
#define EXP2F exp2f
#endif

__device__ inline float bf2f(u16 u) {
  union { uint32_t u; float f; } v; v.u = ((uint32_t)u) << 16; return v.f;
}
__device__ inline u16 f2bf(float f) {
  union { float f; uint32_t u; } v; v.f = f;
  uint32_t r = v.u + 0x7fffu + ((v.u >> 16) & 1u);
  return (u16)(r >> 16);
}
__device__ inline void gl2lds16(const u16* g, u16* l) {
  __builtin_amdgcn_global_load_lds((const __attribute__((address_space(1))) uint32_t*)g,
                                   (__attribute__((address_space(3))) uint32_t*)l, 16, 0, 0);
}

// ---------------- fused prep: x cast + 4 weight transposes + RoPE table ----------------
// R15: transpose restructured to 64k x 32n tiles with short8 (16B/lane) writes:
// old write side was 2B/lane scalar (25% wave efficiency) on a memory-bound
// kernel. Read side unchanged (coalesced fp32). Same values, same addresses.
// blocks: 8192 cast | 5120 wtrans | 512 rtab  -> grid 13824
__global__ void prep_k(const float* __restrict__ x, u16* __restrict__ Xb,
                       const float* __restrict__ Wq, const float* __restrict__ Wk,
                       const float* __restrict__ Wv, const float* __restrict__ Wo,
                       u16* __restrict__ WT, u16* __restrict__ WoT,
                       const int* __restrict__ pos, float2* __restrict__ rtab) {
  __shared__ u16 tile[64][33];
  const int b = blockIdx.x, t = threadIdx.x;
  if (b < 8192) {  // cast
    int i = b * 256 + t;
    float4 v = ((const float4*)x)[i];
    ushort4 o;
    o.x = f2bf(v.x); o.y = f2bf(v.y); o.z = f2bf(v.z); o.w = f2bf(v.w);
    ((ushort4*)Xb)[i] = o;
    return;
  }
  if (b >= 13312) {  // RoPE table (512 blocks)
    int i = (b - 13312) * 256 + t;  // 0..131071
    int s = i >> 6, d = i & 63;
    float freq = __expf(-(float)d * 0.015625f * 9.210340371976184f);
    float ang = (float)pos[s] * freq;
    rtab[i] = make_float2(cosf(ang), sinf(ang));
    return;
  }
  int wb = b - 8192;  // 0..5119
  const float* src; u16* dst; int bx, by, N;
  if (wb < 2048)      { src = Wq; dst = WT;                       bx = wb & 63;          by = wb >> 6;          N = 2048; }
  else if (wb < 2560) { src = Wk; dst = WT + (size_t)2048 * 2048; bx = (wb - 2048) & 15; by = (wb - 2048) >> 4; N = 512;  }
  else if (wb < 3072) { src = Wv; dst = WT + (size_t)2560 * 2048; bx = (wb - 2560) & 15; by = (wb - 2560) >> 4; N = 512;  }
  else                { src = Wo; dst = WoT;                      bx = (wb - 3072) & 63; by = (wb - 3072) >> 6; N = 2048; }
  int n0 = bx * 32, k0 = by * 64;
  int tx = t & 31, ty = t >> 5;  // 32 x 8
#pragma unroll
  for (int i = 0; i < 8; i++)
    tile[ty + 8 * i][tx] = f2bf(src[(size_t)(k0 + ty + 8 * i) * N + n0 + tx]);
  __syncthreads();
  // write: lane t -> row n = t>>3, cols kc..kc+7 (one 16B store; 8 lanes = 128B run)
  int n = t >> 3, kc = (t & 7) * 8;
  short8 v;
#pragma unroll
  for (int j = 0; j < 8; j++) v[j] = (short)tile[kc + j][n];
  *(short8*)(dst + (size_t)(n0 + n) * 2048 + k0 + kc) = v;
}

// ---------------- GEMM 128x128, fp32 out (Wo projection) — unchanged from R13 ----------------
__global__ __launch_bounds__(256) void gemm128_k(const u16* __restrict__ A,
                                                 const u16* __restrict__ Bt,
                                                 float* __restrict__ C, int M, int N, int K) {
  __shared__ u16 Al[2][8192];  // [buf][128 rows][64 cols u16], slot-swizzled
  __shared__ u16 Bl[2][8192];
  const int TN = N >> 7;
  int flat = blockIdx.x;
  const int cpx = gridDim.x >> 3;
  flat = (flat & 7) * cpx + (flat >> 3);
  const int m0 = (flat / TN) << 7, n0 = (flat % TN) << 7;
  const int t = threadIdx.x, w = t >> 6, lane = t & 63;
  const int quad = lane >> 4, l16 = lane & 15;
  const int wm = w >> 1, wn = w & 1;
  const int sr = t >> 3, sl = t & 7;  // staging: row-in-round (32/round), 16B slot
  floatx4 acc[4][4] = {};
  const int NKT = K >> 6;
  const int ra_l = wm * 64 + l16;
  const int rb_l = wn * 64 + l16;

  // prologue: stage kt0 -> buf0, full drain once
#pragma unroll
  for (int round = 0; round < 4; round++) {
    int r = round * 32 + sr;
    int so = (sl ^ (r & 7)) << 3;
    gl2lds16(A + (size_t)(m0 + r) * K + so, &Al[0][0] + round * 2048 + t * 8);
    gl2lds16(Bt + (size_t)(n0 + r) * K + so, &Bl[0][0] + round * 2048 + t * 8);
  }
  asm volatile("s_waitcnt vmcnt(0)" ::: "memory");
  __builtin_amdgcn_s_barrier();

  for (int kt = 0; kt < NKT; kt++) {
    const int cur = kt & 1;
    __builtin_amdgcn_s_barrier();  // WAR: all waves done reading buf[cur^1]
    if (kt + 1 < NKT) {            // prefetch kt+1 into the other buffer
      const int k1 = (kt + 1) << 6;
#pragma unroll
      for (int round = 0; round < 4; round++) {
        int r = round * 32 + sr;
        int so = (sl ^ (r & 7)) << 3;
        gl2lds16(A + (size_t)(m0 + r) * K + k1 + so, &Al[cur ^ 1][0] + round * 2048 + t * 8);
        gl2lds16(Bt + (size_t)(n0 + r) * K + k1 + so, &Bl[cur ^ 1][0] + round * 2048 + t * 8);
      }
      asm volatile("s_waitcnt vmcnt(8)" ::: "memory");  // retires buf[cur]'s 8 loads
    } else {
      asm volatile("s_waitcnt vmcnt(0)" ::: "memory");
    }
    __builtin_amdgcn_s_barrier();  // RAW: buf[cur] landed
    const u16* Ab = &Al[cur][0];
    const u16* Bb = &Bl[cur][0];
    short8 af[4][2], bf[4][2];
#pragma unroll
    for (int mt = 0; mt < 4; mt++) {
      int ra = ra_l + mt * 16;
      const u16* base = Ab + ra * 64;
#pragma unroll
      for (int ks = 0; ks < 2; ks++)
        af[mt][ks] = *(const short8*)(base + (((ks * 4 + quad) ^ (ra & 7)) << 3));
    }
#pragma unroll
    for (int nt = 0; nt < 4; nt++) {
      int rb = rb_l + nt * 16;
      const u16* base = Bb + rb * 64;
#pragma unroll
      for (int ks = 0; ks < 2; ks++)
        bf[nt][ks] = *(const short8*)(base + (((ks * 4 + quad) ^ (rb & 7)) << 3));
    }
    __builtin_amdgcn_s_setprio(1);
#pragma unroll
    for (int mt = 0; mt < 4; mt++)
#pragma unroll
      for (int nt = 0; nt < 4; nt++)
#pragma unroll
        for (int ks = 0; ks < 2; ks++)
          acc[mt][nt] = __builtin_amdgcn_mfma_f32_16x16x32_bf16(af[mt][ks], bf[nt][ks], acc[mt][nt], 0, 0, 0);
    __builtin_amdgcn_s_setprio(0);
  }
  // epilogue: fp32 write
#pragma unroll
  for (int mt = 0; mt < 4; mt++)
#pragma unroll
    for (int nt = 0; nt < 4; nt++)
#pragma unroll
      for (int r = 0; r < 4; r++) {
        int row = m0 + wm * 64 + mt * 16 + quad * 4 + r;
        int col = n0 + wn * 64 + nt * 16 + l16;
        C[(size_t)row * N + col] = acc[mt][nt][r];
      }
}

// ---------------- GEMM 256x256 (R13 verified) + RoPE epilogue + fused V-transpose ----------------
// REVERTED from R14's gemmqkv_k (128^2 tiles doubled HBM fetch 58->110 GB,
// 83.5us). This is the R13 source: fragment reuse B-first, slot-XOR swizzle,
// counted vmcnt(4) w/ last-tile vmcnt(0), RoPE-pair rtab epilogue, fused
// V-transpose repack into QKV's V stripe.
__global__ __launch_bounds__(512, 2) void gemm256_k(const u16* __restrict__ A,
                                                    const u16* __restrict__ Bt,
                                                    u16* __restrict__ C,
                                                    const float2* __restrict__ rtab,
                                                    int N, int K) {
  __shared__ u16 SM[65536];  // 128 KiB: K-loop Al|Bl, then V-transpose buffer
  u16* const AlB = SM;           // [c][half][8192]: c*16384 + half*8192
  u16* const BlB = SM + 32768;
  const int TN = N >> 8;
  int flat = blockIdx.x;
  const int cpx = gridDim.x >> 3;  // grid % 8 == 0 guaranteed by launch config
  flat = (flat & 7) * cpx + (flat >> 3);
  const int m0 = (flat / TN) << 8, n0 = (flat % TN) << 8;
  const int t = threadIdx.x, w = t >> 6, lane = t & 63;
  const int quad = lane >> 4, l16 = lane & 15;
  const int wm = w >> 2, wn = w & 3;
  const int sr = t >> 3, sl = t & 7;  // staging: row-in-round, lds slot
  floatx4 acc[2][2][4][2] = {};
  const int NKT = K >> 6;

  const int ra_l = wm * 64 + l16;  // + mt*16 ; A row within 128-half
  const int rb_l = wn * 16 + l16;  // + nt*64 ; B row within 128-half (RoPE-pair remap)

  // prologue: stage kt0 into buf0 (A0,B0,B1,A1), full drain once
#pragma unroll
  for (int round = 0; round < 2; round++) {
    int r = round * 64 + sr;
    int so = (sl ^ (r & 7)) << 3;
    gl2lds16(A + (size_t)(m0 + r) * K + so, AlB + round * 4096 + t * 8);
    gl2lds16(Bt + (size_t)(n0 + r) * K + so, BlB + round * 4096 + t * 8);
    gl2lds16(Bt + (size_t)(n0 + 128 + r) * K + so, BlB + 8192 + round * 4096 + t * 8);
    gl2lds16(A + (size_t)(m0 + 128 + r) * K + so, AlB + 8192 + round * 4096 + t * 8);
  }
  asm volatile("s_waitcnt vmcnt(0)" ::: "memory");
  __builtin_amdgcn_s_barrier();

  short8 af[4][2];     // current A-half fragments (reused by 2 phases)
  short8 bf[2][2][2];  // [nh][nt][ks] both B-half fragments

  for (int kt = 0; kt < NKT; kt++) {
    const int c = kt & 1;
    const u16* Ab = AlB + c * 16384;
    const u16* Bb = BlB + c * 16384;
    u16* An = AlB + (c ^ 1) * 16384;
    u16* Bn = BlB + (c ^ 1) * 16384;
    const int k1 = (kt + 1) << 6;
    const bool pf = (kt + 1 < NKT);
#pragma unroll
    for (int ph = 0; ph < 4; ph++) {
      // quadrant sequence: (mh,nh) = (0,0),(0,1),(1,1),(1,0)
      const int mh = (ph >> 1);
      const int nh = (ph == 1 || ph == 2) ? 1 : 0;
      // ---- ds-read ONLY the new fragments, B first (first-use order) ----
      if (ph == 0 || ph == 1) {  // new B-half
#pragma unroll
        for (int nt = 0; nt < 2; nt++) {
          int rb = rb_l + nt * 64;
          const u16* base = Bb + nh * 8192 + rb * 64;
#pragma unroll
          for (int ks = 0; ks < 2; ks++)
            bf[nh][nt][ks] = *(const short8*)(base + (((ks * 4 + quad) ^ (rb & 7)) << 3));
        }
      }
      if (ph == 0 || ph == 2) {  // new A-half
#pragma unroll
        for (int mt = 0; mt < 4; mt++) {
          int ra = ra_l + mt * 16;
          const u16* base = Ab + mh * 8192 + ra * 64;
#pragma unroll
          for (int ks = 0; ks < 2; ks++)
            af[mt][ks] = *(const short8*)(base + (((ks * 4 + quad) ^ (ra & 7)) << 3));
        }
      }
      // ---- stage one half-tile of kt+1 (order A0,B0,B1,A1) ----
      if (pf) {
        const u16* G;
        u16* L;
        int rbase;
        if (ph == 0)      { G = A;  L = An;        rbase = m0; }
        else if (ph == 1) { G = Bt; L = Bn;        rbase = n0; }
        else if (ph == 2) { G = Bt; L = Bn + 8192; rbase = n0 + 128; }
        else              { G = A;  L = An + 8192; rbase = m0 + 128; }
#pragma unroll
        for (int round = 0; round < 2; round++) {
          int r = round * 64 + sr;
          gl2lds16(G + (size_t)(rbase + r) * K + k1 + ((sl ^ (r & 7)) << 3),
                   L + round * 4096 + t * 8);
        }
      }
      __builtin_amdgcn_s_barrier();
      // (no lgkmcnt(0): compiler emits progressive counted waits per MFMA)
      __builtin_amdgcn_s_setprio(1);
#pragma unroll
      for (int mt = 0; mt < 4; mt++)
#pragma unroll
        for (int nt = 0; nt < 2; nt++)
#pragma unroll
          for (int ks = 0; ks < 2; ks++)
            acc[mh][nh][mt][nt] =
                __builtin_amdgcn_mfma_f32_16x16x32_bf16(af[mt][ks], bf[nh][nt][ks], acc[mh][nh][mt][nt], 0, 0, 0);
      __builtin_amdgcn_s_setprio(0);
      if (ph != 2) {
        if (pf) asm volatile("s_waitcnt vmcnt(4)" ::: "memory");
        else    asm volatile("s_waitcnt vmcnt(0)" ::: "memory");  // race fix + LDS-reuse safety
      }
      __builtin_amdgcn_s_barrier();
    }
  }
  if (n0 < 2560) {
    // ---- epilogue: RoPE from table (Q/K tiles) + bf16 write ----
    const int dloc = wn * 16 + l16;
#pragma unroll
    for (int mh = 0; mh < 2; mh++)
#pragma unroll
      for (int mt = 0; mt < 4; mt++)
#pragma unroll
        for (int r = 0; r < 4; r++) {
          int row = m0 + mh * 128 + wm * 64 + mt * 16 + quad * 4 + r;
          float2 cs = rtab[(row & (S_LEN - 1)) * 64 + dloc];
#pragma unroll
          for (int nh = 0; nh < 2; nh++) {
            float a0 = acc[mh][nh][mt][0][r], a1 = acc[mh][nh][mt][1][r];
            float o0 = a0 * cs.x - a1 * cs.y;
            float o1 = a1 * cs.x + a0 * cs.y;
            int colb = n0 + nh * 128 + wn * 16 + l16;
            C[(size_t)row * N + colb]      = f2bf(o0);
            C[(size_t)row * N + colb + 64] = f2bf(o1);
          }
        }
  } else {
    // ---- epilogue: V-tiles -> transposed repack into QKV's V stripe ----
    const int bbv = m0 >> 11, m0loc = m0 & 2047;
    const int kvbase = (n0 - 2560) >> 7;
    // scatter acc -> SM[lcol][lrow ^ ((lcol&15)<<3)] (b64: 4 r-values per store)
#pragma unroll
    for (int mh = 0; mh < 2; mh++)
#pragma unroll
      for (int nh = 0; nh < 2; nh++)
#pragma unroll
        for (int mt = 0; mt < 4; mt++)
#pragma unroll
          for (int pair = 0; pair < 2; pair++) {
            int lrow = mh * 128 + wm * 64 + mt * 16 + quad * 4;
            int lcol = nh * 128 + wn * 16 + l16 + pair * 64;
            short4v v4 = { (short)f2bf(acc[mh][nh][mt][pair][0]),
                           (short)f2bf(acc[mh][nh][mt][pair][1]),
                           (short)f2bf(acc[mh][nh][mt][pair][2]),
                           (short)f2bf(acc[mh][nh][mt][pair][3]) };
            *(short4v*)(SM + lcol * 256 + (lrow ^ ((lcol & 15) << 3))) = v4;
          }
    asm volatile("s_waitcnt lgkmcnt(0)" ::: "memory");
    __builtin_amdgcn_s_barrier();
    // gather rows of V^T (contiguous keys) -> coalesced global stores
#pragma unroll
    for (int it = 0; it < 16; it++) {
      int u = it * 512 + t;
      int key0 = (u & 31) * 8, lcol = u >> 5;
      short8 v = *(const short8*)(SM + lcol * 256 + (key0 ^ ((lcol & 15) << 3)));
      int d = lcol & 127, kvh = kvbase + (lcol >> 7);
      int key = m0loc + key0;
      *(short8*)(C + (size_t)(bbv * 2048 + kvh * 512 + d * 4 + (key >> 9)) * N + 2560 + (key & 511)) = v;
    }
  }
}

// ---------------- Flash attention, causal GQA (unchanged from R12/R13) ----------------
__global__ __launch_bounds__(256) void attn_k(const u16* __restrict__ qkv,
                                              u16* __restrict__ ctx) {
  __shared__ u16 Kl[2][64 * 128];      // 2 x 16384 B, [pos][d] swizzled, rows kperm'd
  __shared__ u16 Vl[2][128 * 64];      // 2 x 16384 B, [d][key] swizzled
  const int f = blockIdx.x;
  const int p = f >> 5;
  const int hb = f & 31;
  const int h = hb & 15, bb = hb >> 4;
  const int kvh = h >> 2;
  const int t = threadIdx.x, w = t >> 6, lane = t & 63;
  const int quad = lane >> 4, l16 = lane & 15;
  const int sx = l16 & 7;              // read-side swizzle key
  const int kslot = lane & 15;
  const int vd0 = w * 32 + (lane >> 3);
  const int vslot = lane & 7;
  const int grow0 = (w & 1) * 4 + (w >> 1) * 32 + quad;
  const size_t rowbase = (size_t)bb * S_LEN;
  const u16* Kg0 = qkv + rowbase * NQKV + 2048 + kvh * 128;
  const u16* Vg0 = qkv + (rowbase + kvh * 512) * NQKV + 2560;  // repacked V stripe base
  const float c2 = 0.12751744f;  // (1/sqrt(128)) * log2(e)
  short8 onesf = {16256, 16256, 16256, 16256, 16256, 16256, 16256, 16256};  // bf16 1.0 x8

  for (int phase = 0; phase < 2; phase++) {
    const int qt = phase ? p : 31 - p;  // q-tile index; qt+1 k-iters
    const int rw = qt * 64 + w * 16;    // this wave's first q-row
    const int qrow = rw + l16;          // this lane's q-row (swapped layout: col=q)

    short8 qf[4];
#pragma unroll
    for (int ks = 0; ks < 4; ks++)
      qf[ks] = *(const short8*)(qkv + (rowbase + rw + l16) * NQKV + h * 128 + ks * 32 + quad * 8);

    floatx4 acc[8] = {};
    floatx4 accl = {0.f, 0.f, 0.f, 0.f};

    __syncthreads();  // cross-phase WAR: protect buf0 from previous phase's reads
    // prologue DMA: kb=0 -> buffer 0
    {
#pragma unroll
      for (int ii = 0; ii < 4; ii++) {
        int p7 = (quad + 4 * ii) & 7;  // (position)&7 for the slot swizzle
        int grow = grow0 + 8 * ii;     // permuted global key row
        gl2lds16(Kg0 + (size_t)grow * NQKV + ((kslot ^ p7) * 8),
                 &Kl[0][0] + w * 2048 + ii * 512 + lane * 8);
      }
#pragma unroll
      for (int ii = 0; ii < 4; ii++) {
        int d = vd0 + ii * 8;
        int s8 = (vslot ^ (d & 7)) * 8;
        gl2lds16(Vg0 + (size_t)(d * 4) * NQKV + s8,  // kb=0
                 &Vl[0][0] + w * 2048 + ii * 512 + lane * 8);
      }
    }

    for (int kb = 0; kb <= qt; kb++) {
      const int cur = kb & 1;
      __builtin_amdgcn_s_barrier();  // WAR: all waves done reading buf[cur^1]
      if (kb < qt) {    // prefetch kb+1 into the other buffer
        const int kn = kb + 1;
        const u16* Kg = Kg0 + (size_t)kn * 64 * NQKV;
        u16* KlN = &Kl[cur ^ 1][0];
        u16* VlN = &Vl[cur ^ 1][0];
#pragma unroll
        for (int ii = 0; ii < 4; ii++) {
          int p7 = (quad + 4 * ii) & 7;
          int grow = grow0 + 8 * ii;
          gl2lds16(Kg + (size_t)grow * NQKV + ((kslot ^ p7) * 8),
                   KlN + w * 2048 + ii * 512 + lane * 8);
        }
#pragma unroll
        for (int ii = 0; ii < 4; ii++) {
          int d = vd0 + ii * 8;
          int s8 = (vslot ^ (d & 7)) * 8;
          gl2lds16(Vg0 + (size_t)(d * 4 + (kn >> 3)) * NQKV + (kn & 7) * 64 + s8,
                   VlN + w * 2048 + ii * 512 + lane * 8);
        }
        asm volatile("s_waitcnt vmcnt(8)" ::: "memory");  // buf[cur]'s 8 loads done
      } else {
        asm volatile("s_waitcnt vmcnt(0)" ::: "memory");  // last iter: full drain
      }
      __builtin_amdgcn_s_barrier();  // RAW: all waves' buf[cur] loads landed
      const u16* KlB = &Kl[cur][0];
      const u16* VlB = &Vl[cur][0];

      // ---- QK^T (swapped: A=K, B=Q -> lane holds S[pos=quad*4+r][q=l16]) ----
      floatx4 sc[4];
      __builtin_amdgcn_s_setprio(1);
#pragma unroll
      for (int nt = 0; nt < 4; nt++) {
        const u16* Krow = KlB + (nt * 16 + l16) * 128;
        short8 kf[4];
#pragma unroll
        for (int ks = 0; ks < 4; ks++)
          kf[ks] = *(const short8*)(Krow + (((ks * 4 + quad) ^ sx) * 8));
        floatx4 s = {0.f, 0.f, 0.f, 0.f};
#pragma unroll
        for (int ks = 0; ks < 4; ks++) s = __builtin_amdgcn_mfma_f32_16x16x32_bf16(kf[ks], qf[ks], s, 0, 0, 0);
        sc[nt] = s;
      }
      __builtin_amdgcn_s_setprio(0);
      // ---- P = exp2(score*c2), causal mask, trunc-pack DIRECTLY into A-frags ----
      const bool diag = (kb == qt);
      uint32_t pw[8];
#pragma unroll
      for (int nt = 0; nt < 4; nt++) {
        uint32_t w0 = 0, w1 = 0;
#pragma unroll
        for (int r = 0; r < 4; r++) {
          float e = EXP2F(sc[nt][r] * c2);
          if (diag) {
            int keyg = kb * 64 + quad * 8 + (nt & 1) * 4 + (nt >> 1) * 32 + r;
            if (keyg > qrow) e = 0.f;
          }
          uint32_t b = __float_as_uint(e) >> 16;
          if (r == 0) w0 = b;
          else if (r == 1) w0 |= b << 16;
          else if (r == 2) w1 = b;
          else w1 |= b << 16;
        }
        pw[nt * 2] = w0;
        pw[nt * 2 + 1] = w1;
      }
      union { short8 v; uint32_t u[4]; } pu0, pu1;
      pu0.u[0] = pw[0]; pu0.u[1] = pw[1]; pu0.u[2] = pw[2]; pu0.u[3] = pw[3];
      pu1.u[0] = pw[4]; pu1.u[1] = pw[5]; pu1.u[2] = pw[6]; pu1.u[3] = pw[7];
      const short8 pf0 = pu0.v, pf1 = pu1.v;  // PV A-frags, keys 0-31 / 32-63

      // ---- PV (+ ones-column row-sum into accl) ----
      __builtin_amdgcn_s_setprio(1);
      accl = __builtin_amdgcn_mfma_f32_16x16x32_bf16(pf0, onesf, accl, 0, 0, 0);
      accl = __builtin_amdgcn_mfma_f32_16x16x32_bf16(pf1, onesf, accl, 0, 0, 0);
#pragma unroll
      for (int nto = 0; nto < 8; nto++) {
        const u16* Vrow = VlB + (nto * 16 + l16) * 64;
        short8 vf0 = *(const short8*)(Vrow + ((quad ^ sx) * 8));
        short8 vf1 = *(const short8*)(Vrow + (((quad + 4) ^ sx) * 8));
        acc[nto] = __builtin_amdgcn_mfma_f32_16x16x32_bf16(pf0, vf0, acc[nto], 0, 0, 0);
        acc[nto] = __builtin_amdgcn_mfma_f32_16x16x32_bf16(pf1, vf1, acc[nto], 0, 0, 0);
      }
      __builtin_amdgcn_s_setprio(0);
    }
    // ---- epilogue for this q-tile (lane holds O[q=quad*4+r][d=l16]) ----
#pragma unroll
    for (int r = 0; r < 4; r++) {
      float inv = 1.0f / accl[r];
      int rowg = rw + quad * 4 + r;
#pragma unroll
      for (int nto = 0; nto < 8; nto++) {
        int col = h * 128 + nto * 16 + l16;
        ctx[(rowbase + rowg) * 2048 + col] = f2bf(acc[nto][r] * inv);
      }
    }
  }
}

extern "C" void kernel_launch(void* const* d_in, const int* in_sizes, int n_in,
                              void* d_out, int out_size, void* d_ws, size_t ws_size,
                              hipStream_t stream) {
  const float* x  = (const float*)d_in[0];
  const int* pos  = (const int*)d_in[1];
  const float* Wq = (const float*)d_in[2];
  const float* Wk = (const float*)d_in[3];
  const float* Wv = (const float*)d_in[4];
  const float* Wo = (const float*)d_in[5];
  float* out = (float*)d_out;
  char* ws = (char*)d_ws;
  // ws layout (bf16): Xb[4096][2048] | WT[3072][2048] | WoT[2048][2048] | QKV[4096][3072] | CTX[4096][2048]
  u16* Xb  = (u16*)(ws);
  u16* WT  = (u16*)(ws + 16777216);
  u16* WoT = (u16*)(ws + 29360128);
  u16* QKV = (u16*)(ws + 37748736);
  u16* CTX = (u16*)(ws + 62914560);
  // rtab aliases CTX start (1 MB): written by prep_k, read by gemm256_k,
  // then CTX is overwritten by attn_k (stream-ordered, safe).
  float2* rtab = (float2*)(ws + 62914560);

  // prep: 8192 cast + 5120 transpose + 512 rtab blocks
  hipLaunchKernelGGL(prep_k, dim3(13824), dim3(256), 0, stream, x, Xb, Wq, Wk, Wv, Wo, WT, WoT, pos, rtab);

  // QKV projection + fused RoPE + fused V-repack: grid 192 (192%8==0)
  hipLaunchKernelGGL(gemm256_k, dim3(192), dim3(512), 0, stream, Xb, WT, QKV, rtab, 3072, 2048);
  hipLaunchKernelGGL(attn_k, dim3(512), dim3(256), 0, stream, QKV, CTX);
  // Wo projection: 4096x2048x2048, grid 512 (512%8==0)
  hipLaunchKernelGGL(gemm128_k, dim3(512), dim3(256), 0, stream, CTX, WoT, out, 4096, 2048, 2048);
}

// Round 16
// 264.604 us; speedup vs baseline: 1.0685x; 1.0183x over previous
//
#include <hip/hip_runtime.h>
#include <stdint.h>

typedef unsigned short u16;
typedef __attribute__((ext_vector_type(8))) short short8;
typedef __attribute__((ext_vector_type(4))) short short4v;
typedef __attribute__((ext_vector_type(4))) float floatx4;

#define S_LEN 2048
#define NQKV 3072

#if __has_builtin(__builtin_amdgcn_exp2f)
#define EXP2F __builtin_amdgcn_exp2f
#else
#define EXP2F exp2f
#endif

__device__ inline float bf2f(u16 u) {
  union { uint32_t u; float f; } v; v.u = ((uint32_t)u) << 16; return v.f;
}
__device__ inline u16 f2bf(float f) {
  union { float f; uint32_t u; } v; v.f = f;
  uint32_t r = v.u + 0x7fffu + ((v.u >> 16) & 1u);
  return (u16)(r >> 16);
}
__device__ inline void gl2lds16(const u16* g, u16* l) {
  __builtin_amdgcn_global_load_lds((const __attribute__((address_space(1))) uint32_t*)g,
                                   (__attribute__((address_space(3))) uint32_t*)l, 16, 0, 0);
}

// ---------------- fused prep: x cast + 4 weight transposes + RoPE table ----------------
// (R15-verified: 64k x 32n transpose tiles, short8 16B/lane writes.)
__global__ void prep_k(const float* __restrict__ x, u16* __restrict__ Xb,
                       const float* __restrict__ Wq, const float* __restrict__ Wk,
                       const float* __restrict__ Wv, const float* __restrict__ Wo,
                       u16* __restrict__ WT, u16* __restrict__ WoT,
                       const int* __restrict__ pos, float2* __restrict__ rtab) {
  __shared__ u16 tile[64][33];
  const int b = blockIdx.x, t = threadIdx.x;
  if (b < 8192) {  // cast
    int i = b * 256 + t;
    float4 v = ((const float4*)x)[i];
    ushort4 o;
    o.x = f2bf(v.x); o.y = f2bf(v.y); o.z = f2bf(v.z); o.w = f2bf(v.w);
    ((ushort4*)Xb)[i] = o;
    return;
  }
  if (b >= 13312) {  // RoPE table (512 blocks)
    int i = (b - 13312) * 256 + t;  // 0..131071
    int s = i >> 6, d = i & 63;
    float freq = __expf(-(float)d * 0.015625f * 9.210340371976184f);
    float ang = (float)pos[s] * freq;
    rtab[i] = make_float2(cosf(ang), sinf(ang));
    return;
  }
  int wb = b - 8192;  // 0..5119
  const float* src; u16* dst; int bx, by, N;
  if (wb < 2048)      { src = Wq; dst = WT;                       bx = wb & 63;          by = wb >> 6;          N = 2048; }
  else if (wb < 2560) { src = Wk; dst = WT + (size_t)2048 * 2048; bx = (wb - 2048) & 15; by = (wb - 2048) >> 4; N = 512;  }
  else if (wb < 3072) { src = Wv; dst = WT + (size_t)2560 * 2048; bx = (wb - 2560) & 15; by = (wb - 2560) >> 4; N = 512;  }
  else                { src = Wo; dst = WoT;                      bx = (wb - 3072) & 63; by = (wb - 3072) >> 6; N = 2048; }
  int n0 = bx * 32, k0 = by * 64;
  int tx = t & 31, ty = t >> 5;  // 32 x 8
#pragma unroll
  for (int i = 0; i < 8; i++)
    tile[ty + 8 * i][tx] = f2bf(src[(size_t)(k0 + ty + 8 * i) * N + n0 + tx]);
  __syncthreads();
  // write: lane t -> row n = t>>3, cols kc..kc+7 (one 16B store; 8 lanes = 128B run)
  int n = t >> 3, kc = (t & 7) * 8;
  short8 v;
#pragma unroll
  for (int j = 0; j < 8; j++) v[j] = (short)tile[kc + j][n];
  *(short8*)(dst + (size_t)(n0 + n) * 2048 + k0 + kc) = v;
}

// ---------------- GEMM 128x128, fp32 out (Wo projection) — unchanged from R13 ----------------
__global__ __launch_bounds__(256) void gemm128_k(const u16* __restrict__ A,
                                                 const u16* __restrict__ Bt,
                                                 float* __restrict__ C, int M, int N, int K) {
  __shared__ u16 Al[2][8192];  // [buf][128 rows][64 cols u16], slot-swizzled
  __shared__ u16 Bl[2][8192];
  const int TN = N >> 7;
  int flat = blockIdx.x;
  const int cpx = gridDim.x >> 3;
  flat = (flat & 7) * cpx + (flat >> 3);
  const int m0 = (flat / TN) << 7, n0 = (flat % TN) << 7;
  const int t = threadIdx.x, w = t >> 6, lane = t & 63;
  const int quad = lane >> 4, l16 = lane & 15;
  const int wm = w >> 1, wn = w & 1;
  const int sr = t >> 3, sl = t & 7;  // staging: row-in-round (32/round), 16B slot
  floatx4 acc[4][4] = {};
  const int NKT = K >> 6;
  const int ra_l = wm * 64 + l16;
  const int rb_l = wn * 64 + l16;

  // prologue: stage kt0 -> buf0, full drain once
#pragma unroll
  for (int round = 0; round < 4; round++) {
    int r = round * 32 + sr;
    int so = (sl ^ (r & 7)) << 3;
    gl2lds16(A + (size_t)(m0 + r) * K + so, &Al[0][0] + round * 2048 + t * 8);
    gl2lds16(Bt + (size_t)(n0 + r) * K + so, &Bl[0][0] + round * 2048 + t * 8);
  }
  asm volatile("s_waitcnt vmcnt(0)" ::: "memory");
  __builtin_amdgcn_s_barrier();

  for (int kt = 0; kt < NKT; kt++) {
    const int cur = kt & 1;
    __builtin_amdgcn_s_barrier();  // WAR: all waves done reading buf[cur^1]
    if (kt + 1 < NKT) {            // prefetch kt+1 into the other buffer
      const int k1 = (kt + 1) << 6;
#pragma unroll
      for (int round = 0; round < 4; round++) {
        int r = round * 32 + sr;
        int so = (sl ^ (r & 7)) << 3;
        gl2lds16(A + (size_t)(m0 + r) * K + k1 + so, &Al[cur ^ 1][0] + round * 2048 + t * 8);
        gl2lds16(Bt + (size_t)(n0 + r) * K + k1 + so, &Bl[cur ^ 1][0] + round * 2048 + t * 8);
      }
      asm volatile("s_waitcnt vmcnt(8)" ::: "memory");  // retires buf[cur]'s 8 loads
    } else {
      asm volatile("s_waitcnt vmcnt(0)" ::: "memory");
    }
    __builtin_amdgcn_s_barrier();  // RAW: buf[cur] landed
    const u16* Ab = &Al[cur][0];
    const u16* Bb = &Bl[cur][0];
    short8 af[4][2], bf[4][2];
#pragma unroll
    for (int mt = 0; mt < 4; mt++) {
      int ra = ra_l + mt * 16;
      const u16* base = Ab + ra * 64;
#pragma unroll
      for (int ks = 0; ks < 2; ks++)
        af[mt][ks] = *(const short8*)(base + (((ks * 4 + quad) ^ (ra & 7)) << 3));
    }
#pragma unroll
    for (int nt = 0; nt < 4; nt++) {
      int rb = rb_l + nt * 16;
      const u16* base = Bb + rb * 64;
#pragma unroll
      for (int ks = 0; ks < 2; ks++)
        bf[nt][ks] = *(const short8*)(base + (((ks * 4 + quad) ^ (rb & 7)) << 3));
    }
    __builtin_amdgcn_s_setprio(1);
#pragma unroll
    for (int mt = 0; mt < 4; mt++)
#pragma unroll
      for (int nt = 0; nt < 4; nt++)
#pragma unroll
        for (int ks = 0; ks < 2; ks++)
          acc[mt][nt] = __builtin_amdgcn_mfma_f32_16x16x32_bf16(af[mt][ks], bf[nt][ks], acc[mt][nt], 0, 0, 0);
    __builtin_amdgcn_s_setprio(0);
  }
  // epilogue: fp32 write
#pragma unroll
  for (int mt = 0; mt < 4; mt++)
#pragma unroll
    for (int nt = 0; nt < 4; nt++)
#pragma unroll
      for (int r = 0; r < 4; r++) {
        int row = m0 + wm * 64 + mt * 16 + quad * 4 + r;
        int col = n0 + wn * 64 + nt * 16 + l16;
        C[(size_t)row * N + col] = acc[mt][nt][r];
      }
}

// ---------------- GEMM 256x256 (R16): barrier-minimal K-tile ----------------
// R15 cycle model: per K-tile per CU, LDS reads 2304cy + MFMA 2483cy = measured
// 5150cy -- ZERO pipe overlap. Cause: the 8 intra-tile barriers (2/phase) lock
// all 8 waves (one barrier group at 1 block/CU) into {read-burst | MFMA-burst}
// alternation. Audit: intra-tile barriers protect NOTHING -- all tile reads hit
// buf[c], all stages write buf[c^1]. Only tile-boundary hazards exist (RAW:
// kt-1 stages -> kt reads; WAR: kt-1 reads -> kt stages), both covered by ONE
// vmcnt(0)+s_barrier per tile. vmcnt(0) is cheap: the 8 stages are issued at
// tile START, ~2400cy before the wait. Fragment flow and MFMA accumulation
// order IDENTICAL to R13 (stage-first; read B0,A0 -> q00 -> read B1 -> q01 ->
// read A1 -> q11 -> q10) -> bit-identical output; compiler now free to overlap
// reads under MFMAs within a wave, waves skew across the tile.
// (Epilogues unchanged: RoPE-pair rtab for Q/K tiles; V-transpose repack.)
__global__ __launch_bounds__(512, 2) void gemm256_k(const u16* __restrict__ A,
                                                    const u16* __restrict__ Bt,
                                                    u16* __restrict__ C,
                                                    const float2* __restrict__ rtab,
                                                    int N, int K) {
  __shared__ u16 SM[65536];  // 128 KiB: K-loop Al|Bl, then V-transpose buffer
  u16* const AlB = SM;           // [c][half][8192]: c*16384 + half*8192
  u16* const BlB = SM + 32768;
  const int TN = N >> 8;
  int flat = blockIdx.x;
  const int cpx = gridDim.x >> 3;  // grid % 8 == 0 guaranteed by launch config
  flat = (flat & 7) * cpx + (flat >> 3);
  const int m0 = (flat / TN) << 8, n0 = (flat % TN) << 8;
  const int t = threadIdx.x, w = t >> 6, lane = t & 63;
  const int quad = lane >> 4, l16 = lane & 15;
  const int wm = w >> 2, wn = w & 3;
  const int sr = t >> 3, sl = t & 7;  // staging: row-in-round, lds slot
  floatx4 acc[2][2][4][2] = {};
  const int NKT = K >> 6;

  const int ra_l = wm * 64 + l16;  // + mt*16 ; A row within 128-half
  const int rb_l = wn * 16 + l16;  // + nt*64 ; B row within 128-half (RoPE-pair remap)

  // prologue: stage kt0 into buf0 (A0,B0,B1,A1), full drain once
#pragma unroll
  for (int round = 0; round < 2; round++) {
    int r = round * 64 + sr;
    int so = (sl ^ (r & 7)) << 3;
    gl2lds16(A + (size_t)(m0 + r) * K + so, AlB + round * 4096 + t * 8);
    gl2lds16(Bt + (size_t)(n0 + r) * K + so, BlB + round * 4096 + t * 8);
    gl2lds16(Bt + (size_t)(n0 + 128 + r) * K + so, BlB + 8192 + round * 4096 + t * 8);
    gl2lds16(A + (size_t)(m0 + 128 + r) * K + so, AlB + 8192 + round * 4096 + t * 8);
  }
  asm volatile("s_waitcnt vmcnt(0)" ::: "memory");
  __builtin_amdgcn_s_barrier();

  short8 af[4][2];     // current A-half fragments (reused by 2 quadrants)
  short8 bf[2][2][2];  // [nh][nt][ks] both B-half fragments

  for (int kt = 0; kt < NKT; kt++) {
    const int c = kt & 1;
    const u16* Ab = AlB + c * 16384;
    const u16* Bb = BlB + c * 16384;
    u16* An = AlB + (c ^ 1) * 16384;
    u16* Bn = BlB + (c ^ 1) * 16384;
    // ---- stage kt+1 (8 DMAs) FIRST: maximal in-flight time before tile-end wait ----
    if (kt + 1 < NKT) {
      const int k1 = (kt + 1) << 6;
#pragma unroll
      for (int round = 0; round < 2; round++) {
        int r = round * 64 + sr;
        int so = (sl ^ (r & 7)) << 3;
        gl2lds16(A + (size_t)(m0 + r) * K + k1 + so, An + round * 4096 + t * 8);
        gl2lds16(Bt + (size_t)(n0 + r) * K + k1 + so, Bn + round * 4096 + t * 8);
        gl2lds16(Bt + (size_t)(n0 + 128 + r) * K + k1 + so, Bn + 8192 + round * 4096 + t * 8);
        gl2lds16(A + (size_t)(m0 + 128 + r) * K + k1 + so, An + 8192 + round * 4096 + t * 8);
      }
    }
    // ---- full tile: reads + MFMAs, NO intra-tile barriers ----
    __builtin_amdgcn_s_setprio(1);
    // B0 + A0
#pragma unroll
    for (int nt = 0; nt < 2; nt++) {
      int rb = rb_l + nt * 64;
      const u16* base = Bb + rb * 64;
#pragma unroll
      for (int ks = 0; ks < 2; ks++)
        bf[0][nt][ks] = *(const short8*)(base + (((ks * 4 + quad) ^ (rb & 7)) << 3));
    }
#pragma unroll
    for (int mt = 0; mt < 4; mt++) {
      int ra = ra_l + mt * 16;
      const u16* base = Ab + ra * 64;
#pragma unroll
      for (int ks = 0; ks < 2; ks++)
        af[mt][ks] = *(const short8*)(base + (((ks * 4 + quad) ^ (ra & 7)) << 3));
    }
    // q00
#pragma unroll
    for (int mt = 0; mt < 4; mt++)
#pragma unroll
      for (int nt = 0; nt < 2; nt++)
#pragma unroll
        for (int ks = 0; ks < 2; ks++)
          acc[0][0][mt][nt] =
              __builtin_amdgcn_mfma_f32_16x16x32_bf16(af[mt][ks], bf[0][nt][ks], acc[0][0][mt][nt], 0, 0, 0);
    // B1
#pragma unroll
    for (int nt = 0; nt < 2; nt++) {
      int rb = rb_l + nt * 64;
      const u16* base = Bb + 8192 + rb * 64;
#pragma unroll
      for (int ks = 0; ks < 2; ks++)
        bf[1][nt][ks] = *(const short8*)(base + (((ks * 4 + quad) ^ (rb & 7)) << 3));
    }
    // q01
#pragma unroll
    for (int mt = 0; mt < 4; mt++)
#pragma unroll
      for (int nt = 0; nt < 2; nt++)
#pragma unroll
        for (int ks = 0; ks < 2; ks++)
          acc[0][1][mt][nt] =
              __builtin_amdgcn_mfma_f32_16x16x32_bf16(af[mt][ks], bf[1][nt][ks], acc[0][1][mt][nt], 0, 0, 0);
    // A1
#pragma unroll
    for (int mt = 0; mt < 4; mt++) {
      int ra = ra_l + mt * 16;
      const u16* base = Ab + 8192 + ra * 64;
#pragma unroll
      for (int ks = 0; ks < 2; ks++)
        af[mt][ks] = *(const short8*)(base + (((ks * 4 + quad) ^ (ra & 7)) << 3));
    }
    // q11
#pragma unroll
    for (int mt = 0; mt < 4; mt++)
#pragma unroll
      for (int nt = 0; nt < 2; nt++)
#pragma unroll
        for (int ks = 0; ks < 2; ks++)
          acc[1][1][mt][nt] =
              __builtin_amdgcn_mfma_f32_16x16x32_bf16(af[mt][ks], bf[1][nt][ks], acc[1][1][mt][nt], 0, 0, 0);
    // q10
#pragma unroll
    for (int mt = 0; mt < 4; mt++)
#pragma unroll
      for (int nt = 0; nt < 2; nt++)
#pragma unroll
        for (int ks = 0; ks < 2; ks++)
          acc[1][0][mt][nt] =
              __builtin_amdgcn_mfma_f32_16x16x32_bf16(af[mt][ks], bf[0][nt][ks], acc[1][0][mt][nt], 0, 0, 0);
    __builtin_amdgcn_s_setprio(0);
    // ---- tile-end: retire own stages, then block-wide sync (RAW+WAR) ----
    asm volatile("s_waitcnt vmcnt(0)" ::: "memory");
    __builtin_amdgcn_s_barrier();
  }
  if (n0 < 2560) {
    // ---- epilogue: RoPE from table (Q/K tiles) + bf16 write ----
    const int dloc = wn * 16 + l16;
#pragma unroll
    for (int mh = 0; mh < 2; mh++)
#pragma unroll
      for (int mt = 0; mt < 4; mt++)
#pragma unroll
        for (int r = 0; r < 4; r++) {
          int row = m0 + mh * 128 + wm * 64 + mt * 16 + quad * 4 + r;
          float2 cs = rtab[(row & (S_LEN - 1)) * 64 + dloc];
#pragma unroll
          for (int nh = 0; nh < 2; nh++) {
            float a0 = acc[mh][nh][mt][0][r], a1 = acc[mh][nh][mt][1][r];
            float o0 = a0 * cs.x - a1 * cs.y;
            float o1 = a1 * cs.x + a0 * cs.y;
            int colb = n0 + nh * 128 + wn * 16 + l16;
            C[(size_t)row * N + colb]      = f2bf(o0);
            C[(size_t)row * N + colb + 64] = f2bf(o1);
          }
        }
  } else {
    // ---- epilogue: V-tiles -> transposed repack into QKV's V stripe ----
    const int bbv = m0 >> 11, m0loc = m0 & 2047;
    const int kvbase = (n0 - 2560) >> 7;
    // scatter acc -> SM[lcol][lrow ^ ((lcol&15)<<3)] (b64: 4 r-values per store)
#pragma unroll
    for (int mh = 0; mh < 2; mh++)
#pragma unroll
      for (int nh = 0; nh < 2; nh++)
#pragma unroll
        for (int mt = 0; mt < 4; mt++)
#pragma unroll
          for (int pair = 0; pair < 2; pair++) {
            int lrow = mh * 128 + wm * 64 + mt * 16 + quad * 4;
            int lcol = nh * 128 + wn * 16 + l16 + pair * 64;
            short4v v4 = { (short)f2bf(acc[mh][nh][mt][pair][0]),
                           (short)f2bf(acc[mh][nh][mt][pair][1]),
                           (short)f2bf(acc[mh][nh][mt][pair][2]),
                           (short)f2bf(acc[mh][nh][mt][pair][3]) };
            *(short4v*)(SM + lcol * 256 + (lrow ^ ((lcol & 15) << 3))) = v4;
          }
    asm volatile("s_waitcnt lgkmcnt(0)" ::: "memory");
    __builtin_amdgcn_s_barrier();
    // gather rows of V^T (contiguous keys) -> coalesced global stores
#pragma unroll
    for (int it = 0; it < 16; it++) {
      int u = it * 512 + t;
      int key0 = (u & 31) * 8, lcol = u >> 5;
      short8 v = *(const short8*)(SM + lcol * 256 + (key0 ^ ((lcol & 15) << 3)));
      int d = lcol & 127, kvh = kvbase + (lcol >> 7);
      int key = m0loc + key0;
      *(short8*)(C + (size_t)(bbv * 2048 + kvh * 512 + d * 4 + (key >> 9)) * N + 2560 + (key & 511)) = v;
    }
  }
}

// ---------------- Flash attention, causal GQA (unchanged from R12/R13) ----------------
__global__ __launch_bounds__(256) void attn_k(const u16* __restrict__ qkv,
                                              u16* __restrict__ ctx) {
  __shared__ u16 Kl[2][64 * 128];      // 2 x 16384 B, [pos][d] swizzled, rows kperm'd
  __shared__ u16 Vl[2][128 * 64];      // 2 x 16384 B, [d][key] swizzled
  const int f = blockIdx.x;
  const int p = f >> 5;
  const int hb = f & 31;
  const int h = hb & 15, bb = hb >> 4;
  const int kvh = h >> 2;
  const int t = threadIdx.x, w = t >> 6, lane = t & 63;
  const int quad = lane >> 4, l16 = lane & 15;
  const int sx = l16 & 7;              // read-side swizzle key
  const int kslot = lane & 15;
  const int vd0 = w * 32 + (lane >> 3);
  const int vslot = lane & 7;
  const int grow0 = (w & 1) * 4 + (w >> 1) * 32 + quad;
  const size_t rowbase = (size_t)bb * S_LEN;
  const u16* Kg0 = qkv + rowbase * NQKV + 2048 + kvh * 128;
  const u16* Vg0 = qkv + (rowbase + kvh * 512) * NQKV + 2560;  // repacked V stripe base
  const float c2 = 0.12751744f;  // (1/sqrt(128)) * log2(e)
  short8 onesf = {16256, 16256, 16256, 16256, 16256, 16256, 16256, 16256};  // bf16 1.0 x8

  for (int phase = 0; phase < 2; phase++) {
    const int qt = phase ? p : 31 - p;  // q-tile index; qt+1 k-iters
    const int rw = qt * 64 + w * 16;    // this wave's first q-row
    const int qrow = rw + l16;          // this lane's q-row (swapped layout: col=q)

    short8 qf[4];
#pragma unroll
    for (int ks = 0; ks < 4; ks++)
      qf[ks] = *(const short8*)(qkv + (rowbase + rw + l16) * NQKV + h * 128 + ks * 32 + quad * 8);

    floatx4 acc[8] = {};
    floatx4 accl = {0.f, 0.f, 0.f, 0.f};

    __syncthreads();  // cross-phase WAR: protect buf0 from previous phase's reads
    // prologue DMA: kb=0 -> buffer 0
    {
#pragma unroll
      for (int ii = 0; ii < 4; ii++) {
        int p7 = (quad + 4 * ii) & 7;  // (position)&7 for the slot swizzle
        int grow = grow0 + 8 * ii;     // permuted global key row
        gl2lds16(Kg0 + (size_t)grow * NQKV + ((kslot ^ p7) * 8),
                 &Kl[0][0] + w * 2048 + ii * 512 + lane * 8);
      }
#pragma unroll
      for (int ii = 0; ii < 4; ii++) {
        int d = vd0 + ii * 8;
        int s8 = (vslot ^ (d & 7)) * 8;
        gl2lds16(Vg0 + (size_t)(d * 4) * NQKV + s8,  // kb=0
                 &Vl[0][0] + w * 2048 + ii * 512 + lane * 8);
      }
    }

    for (int kb = 0; kb <= qt; kb++) {
      const int cur = kb & 1;
      __builtin_amdgcn_s_barrier();  // WAR: all waves done reading buf[cur^1]
      if (kb < qt) {    // prefetch kb+1 into the other buffer
        const int kn = kb + 1;
        const u16* Kg = Kg0 + (size_t)kn * 64 * NQKV;
        u16* KlN = &Kl[cur ^ 1][0];
        u16* VlN = &Vl[cur ^ 1][0];
#pragma unroll
        for (int ii = 0; ii < 4; ii++) {
          int p7 = (quad + 4 * ii) & 7;
          int grow = grow0 + 8 * ii;
          gl2lds16(Kg + (size_t)grow * NQKV + ((kslot ^ p7) * 8),
                   KlN + w * 2048 + ii * 512 + lane * 8);
        }
#pragma unroll
        for (int ii = 0; ii < 4; ii++) {
          int d = vd0 + ii * 8;
          int s8 = (vslot ^ (d & 7)) * 8;
          gl2lds16(Vg0 + (size_t)(d * 4 + (kn >> 3)) * NQKV + (kn & 7) * 64 + s8,
                   VlN + w * 2048 + ii * 512 + lane * 8);
        }
        asm volatile("s_waitcnt vmcnt(8)" ::: "memory");  // buf[cur]'s 8 loads done
      } else {
        asm volatile("s_waitcnt vmcnt(0)" ::: "memory");  // last iter: full drain
      }
      __builtin_amdgcn_s_barrier();  // RAW: all waves' buf[cur] loads landed
      const u16* KlB = &Kl[cur][0];
      const u16* VlB = &Vl[cur][0];

      // ---- QK^T (swapped: A=K, B=Q -> lane holds S[pos=quad*4+r][q=l16]) ----
      floatx4 sc[4];
      __builtin_amdgcn_s_setprio(1);
#pragma unroll
      for (int nt = 0; nt < 4; nt++) {
        const u16* Krow = KlB + (nt * 16 + l16) * 128;
        short8 kf[4];
#pragma unroll
        for (int ks = 0; ks < 4; ks++)
          kf[ks] = *(const short8*)(Krow + (((ks * 4 + quad) ^ sx) * 8));
        floatx4 s = {0.f, 0.f, 0.f, 0.f};
#pragma unroll
        for (int ks = 0; ks < 4; ks++) s = __builtin_amdgcn_mfma_f32_16x16x32_bf16(kf[ks], qf[ks], s, 0, 0, 0);
        sc[nt] = s;
      }
      __builtin_amdgcn_s_setprio(0);
      // ---- P = exp2(score*c2), causal mask, trunc-pack DIRECTLY into A-frags ----
      const bool diag = (kb == qt);
      uint32_t pw[8];
#pragma unroll
      for (int nt = 0; nt < 4; nt++) {
        uint32_t w0 = 0, w1 = 0;
#pragma unroll
        for (int r = 0; r < 4; r++) {
          float e = EXP2F(sc[nt][r] * c2);
          if (diag) {
            int keyg = kb * 64 + quad * 8 + (nt & 1) * 4 + (nt >> 1) * 32 + r;
            if (keyg > qrow) e = 0.f;
          }
          uint32_t b = __float_as_uint(e) >> 16;
          if (r == 0) w0 = b;
          else if (r == 1) w0 |= b << 16;
          else if (r == 2) w1 = b;
          else w1 |= b << 16;
        }
        pw[nt * 2] = w0;
        pw[nt * 2 + 1] = w1;
      }
      union { short8 v; uint32_t u[4]; } pu0, pu1;
      pu0.u[0] = pw[0]; pu0.u[1] = pw[1]; pu0.u[2] = pw[2]; pu0.u[3] = pw[3];
      pu1.u[0] = pw[4]; pu1.u[1] = pw[5]; pu1.u[2] = pw[6]; pu1.u[3] = pw[7];
      const short8 pf0 = pu0.v, pf1 = pu1.v;  // PV A-frags, keys 0-31 / 32-63

      // ---- PV (+ ones-column row-sum into accl) ----
      __builtin_amdgcn_s_setprio(1);
      accl = __builtin_amdgcn_mfma_f32_16x16x32_bf16(pf0, onesf, accl, 0, 0, 0);
      accl = __builtin_amdgcn_mfma_f32_16x16x32_bf16(pf1, onesf, accl, 0, 0, 0);
#pragma unroll
      for (int nto = 0; nto < 8; nto++) {
        const u16* Vrow = VlB + (nto * 16 + l16) * 64;
        short8 vf0 = *(const short8*)(Vrow + ((quad ^ sx) * 8));
        short8 vf1 = *(const short8*)(Vrow + (((quad + 4) ^ sx) * 8));
        acc[nto] = __builtin_amdgcn_mfma_f32_16x16x32_bf16(pf0, vf0, acc[nto], 0, 0, 0);
        acc[nto] = __builtin_amdgcn_mfma_f32_16x16x32_bf16(pf1, vf1, acc[nto], 0, 0, 0);
      }
      __builtin_amdgcn_s_setprio(0);
    }
    // ---- epilogue for this q-tile (lane holds O[q=quad*4+r][d=l16]) ----
#pragma unroll
    for (int r = 0; r < 4; r++) {
      float inv = 1.0f / accl[r];
      int rowg = rw + quad * 4 + r;
#pragma unroll
      for (int nto = 0; nto < 8; nto++) {
        int col = h * 128 + nto * 16 + l16;
        ctx[(rowbase + rowg) * 2048 + col] = f2bf(acc[nto][r] * inv);
      }
    }
  }
}

extern "C" void kernel_launch(void* const* d_in, const int* in_sizes, int n_in,
                              void* d_out, int out_size, void* d_ws, size_t ws_size,
                              hipStream_t stream) {
  const float* x  = (const float*)d_in[0];
  const int* pos  = (const int*)d_in[1];
  const float* Wq = (const float*)d_in[2];
  const float* Wk = (const float*)d_in[3];
  const float* Wv = (const float*)d_in[4];
  const float* Wo = (const float*)d_in[5];
  float* out = (float*)d_out;
  char* ws = (char*)d_ws;
  // ws layout (bf16): Xb[4096][2048] | WT[3072][2048] | WoT[2048][2048] | QKV[4096][3072] | CTX[4096][2048]
  u16* Xb  = (u16*)(ws);
  u16* WT  = (u16*)(ws + 16777216);
  u16* WoT = (u16*)(ws + 29360128);
  u16* QKV = (u16*)(ws + 37748736);
  u16* CTX = (u16*)(ws + 62914560);
  // rtab aliases CTX start (1 MB): written by prep_k, read by gemm256_k,
  // then CTX is overwritten by attn_k (stream-ordered, safe).
  float2* rtab = (float2*)(ws + 62914560);

  // prep: 8192 cast + 5120 transpose + 512 rtab blocks
  hipLaunchKernelGGL(prep_k, dim3(13824), dim3(256), 0, stream, x, Xb, Wq, Wk, Wv, Wo, WT, WoT, pos, rtab);

  // QKV projection + fused RoPE + fused V-repack: grid 192 (192%8==0)
  hipLaunchKernelGGL(gemm256_k, dim3(192), dim3(512), 0, stream, Xb, WT, QKV, rtab, 3072, 2048);
  hipLaunchKernelGGL(attn_k, dim3(512), dim3(256), 0, stream, QKV, CTX);
  // Wo projection: 4096x2048x2048, grid 512 (512%8==0)
  hipLaunchKernelGGL(gemm128_k, dim3(512), dim3(256), 0, stream, CTX, WoT, out, 4096, 2048, 2048);
}

// Round 17
// 263.093 us; speedup vs baseline: 1.0746x; 1.0057x over previous
//
#include <hip/hip_runtime.h>
#include <stdint.h>

typedef unsigned short u16;
typedef __attribute__((ext_vector_type(8))) short short8;
typedef __attribute__((ext_vector_type(4))) short short4v;
typedef __attribute__((ext_vector_type(4))) float floatx4;

#define S_LEN 2048
#define NQKV 3072

#if __has_builtin(__builtin_amdgcn_exp2f)
#define EXP2F __builtin_amdgcn_exp2f
#else
#define EXP2F exp2f
#endif

__device__ inline float bf2f(u16 u) {
  union { uint32_t u; float f; } v; v.u = ((uint32_t)u) << 16; return v.f;
}
__device__ inline u16 f2bf(float f) {
  union { float f; uint32_t u; } v; v.f = f;
  uint32_t r = v.u + 0x7fffu + ((v.u >> 16) & 1u);
  return (u16)(r >> 16);
}
__device__ inline void gl2lds16(const u16* g, u16* l) {
  __builtin_amdgcn_global_load_lds((const __attribute__((address_space(1))) uint32_t*)g,
                                   (__attribute__((address_space(3))) uint32_t*)l, 16, 0, 0);
}

// ---------------- fused prep: x cast + 4 weight transposes + RoPE table ----------------
// (R15-verified: 64k x 32n transpose tiles, short8 16B/lane writes.)
__global__ void prep_k(const float* __restrict__ x, u16* __restrict__ Xb,
                       const float* __restrict__ Wq, const float* __restrict__ Wk,
                       const float* __restrict__ Wv, const float* __restrict__ Wo,
                       u16* __restrict__ WT, u16* __restrict__ WoT,
                       const int* __restrict__ pos, float2* __restrict__ rtab) {
  __shared__ u16 tile[64][33];
  const int b = blockIdx.x, t = threadIdx.x;
  if (b < 8192) {  // cast
    int i = b * 256 + t;
    float4 v = ((const float4*)x)[i];
    ushort4 o;
    o.x = f2bf(v.x); o.y = f2bf(v.y); o.z = f2bf(v.z); o.w = f2bf(v.w);
    ((ushort4*)Xb)[i] = o;
    return;
  }
  if (b >= 13312) {  // RoPE table (512 blocks)
    int i = (b - 13312) * 256 + t;  // 0..131071
    int s = i >> 6, d = i & 63;
    float freq = __expf(-(float)d * 0.015625f * 9.210340371976184f);
    float ang = (float)pos[s] * freq;
    rtab[i] = make_float2(cosf(ang), sinf(ang));
    return;
  }
  int wb = b - 8192;  // 0..5119
  const float* src; u16* dst; int bx, by, N;
  if (wb < 2048)      { src = Wq; dst = WT;                       bx = wb & 63;          by = wb >> 6;          N = 2048; }
  else if (wb < 2560) { src = Wk; dst = WT + (size_t)2048 * 2048; bx = (wb - 2048) & 15; by = (wb - 2048) >> 4; N = 512;  }
  else if (wb < 3072) { src = Wv; dst = WT + (size_t)2560 * 2048; bx = (wb - 2560) & 15; by = (wb - 2560) >> 4; N = 512;  }
  else                { src = Wo; dst = WoT;                      bx = (wb - 3072) & 63; by = (wb - 3072) >> 6; N = 2048; }
  int n0 = bx * 32, k0 = by * 64;
  int tx = t & 31, ty = t >> 5;  // 32 x 8
#pragma unroll
  for (int i = 0; i < 8; i++)
    tile[ty + 8 * i][tx] = f2bf(src[(size_t)(k0 + ty + 8 * i) * N + n0 + tx]);
  __syncthreads();
  // write: lane t -> row n = t>>3, cols kc..kc+7 (one 16B store; 8 lanes = 128B run)
  int n = t >> 3, kc = (t & 7) * 8;
  short8 v;
#pragma unroll
  for (int j = 0; j < 8; j++) v[j] = (short)tile[kc + j][n];
  *(short8*)(dst + (size_t)(n0 + n) * 2048 + k0 + kc) = v;
}

// ---------------- GEMM 128x128, fp32 out (Wo) — R17: barrier-minimal K-tile ----------------
// R16 transform replicated from gemm256 (verified there: -6us, bit-identical):
// stage kt+1 at tile START (in-flight = full tile, was rest-of-tile), no
// mid-tile vmcnt(8)+barrier; ONE vmcnt(0)+s_barrier per tile covers both
// boundary hazards (reads hit buf[cur], stages write buf[cur^1]). 2 blocks/CU
// additionally hide the tile-end drain. MFMA accumulation order unchanged ->
// bit-identical fp32 output.
__global__ __launch_bounds__(256) void gemm128_k(const u16* __restrict__ A,
                                                 const u16* __restrict__ Bt,
                                                 float* __restrict__ C, int M, int N, int K) {
  __shared__ u16 Al[2][8192];  // [buf][128 rows][64 cols u16], slot-swizzled
  __shared__ u16 Bl[2][8192];
  const int TN = N >> 7;
  int flat = blockIdx.x;
  const int cpx = gridDim.x >> 3;
  flat = (flat & 7) * cpx + (flat >> 3);
  const int m0 = (flat / TN) << 7, n0 = (flat % TN) << 7;
  const int t = threadIdx.x, w = t >> 6, lane = t & 63;
  const int quad = lane >> 4, l16 = lane & 15;
  const int wm = w >> 1, wn = w & 1;
  const int sr = t >> 3, sl = t & 7;  // staging: row-in-round (32/round), 16B slot
  floatx4 acc[4][4] = {};
  const int NKT = K >> 6;
  const int ra_l = wm * 64 + l16;
  const int rb_l = wn * 64 + l16;

  // prologue: stage kt0 -> buf0, full drain once
#pragma unroll
  for (int round = 0; round < 4; round++) {
    int r = round * 32 + sr;
    int so = (sl ^ (r & 7)) << 3;
    gl2lds16(A + (size_t)(m0 + r) * K + so, &Al[0][0] + round * 2048 + t * 8);
    gl2lds16(Bt + (size_t)(n0 + r) * K + so, &Bl[0][0] + round * 2048 + t * 8);
  }
  asm volatile("s_waitcnt vmcnt(0)" ::: "memory");
  __builtin_amdgcn_s_barrier();

  for (int kt = 0; kt < NKT; kt++) {
    const int cur = kt & 1;
    // ---- stage kt+1 FIRST (writes buf[cur^1]; prior reads of it ended before
    //      the previous tile-end barrier) ----
    if (kt + 1 < NKT) {
      const int k1 = (kt + 1) << 6;
#pragma unroll
      for (int round = 0; round < 4; round++) {
        int r = round * 32 + sr;
        int so = (sl ^ (r & 7)) << 3;
        gl2lds16(A + (size_t)(m0 + r) * K + k1 + so, &Al[cur ^ 1][0] + round * 2048 + t * 8);
        gl2lds16(Bt + (size_t)(n0 + r) * K + k1 + so, &Bl[cur ^ 1][0] + round * 2048 + t * 8);
      }
    }
    // ---- reads + MFMAs, no intra-tile sync ----
    const u16* Ab = &Al[cur][0];
    const u16* Bb = &Bl[cur][0];
    short8 af[4][2], bf[4][2];
#pragma unroll
    for (int mt = 0; mt < 4; mt++) {
      int ra = ra_l + mt * 16;
      const u16* base = Ab + ra * 64;
#pragma unroll
      for (int ks = 0; ks < 2; ks++)
        af[mt][ks] = *(const short8*)(base + (((ks * 4 + quad) ^ (ra & 7)) << 3));
    }
#pragma unroll
    for (int nt = 0; nt < 4; nt++) {
      int rb = rb_l + nt * 16;
      const u16* base = Bb + rb * 64;
#pragma unroll
      for (int ks = 0; ks < 2; ks++)
        bf[nt][ks] = *(const short8*)(base + (((ks * 4 + quad) ^ (rb & 7)) << 3));
    }
    __builtin_amdgcn_s_setprio(1);
#pragma unroll
    for (int mt = 0; mt < 4; mt++)
#pragma unroll
      for (int nt = 0; nt < 4; nt++)
#pragma unroll
        for (int ks = 0; ks < 2; ks++)
          acc[mt][nt] = __builtin_amdgcn_mfma_f32_16x16x32_bf16(af[mt][ks], bf[nt][ks], acc[mt][nt], 0, 0, 0);
    __builtin_amdgcn_s_setprio(0);
    // ---- tile-end: retire own stages, block-wide sync (RAW+WAR) ----
    asm volatile("s_waitcnt vmcnt(0)" ::: "memory");
    __builtin_amdgcn_s_barrier();
  }
  // epilogue: fp32 write
#pragma unroll
  for (int mt = 0; mt < 4; mt++)
#pragma unroll
    for (int nt = 0; nt < 4; nt++)
#pragma unroll
      for (int r = 0; r < 4; r++) {
        int row = m0 + wm * 64 + mt * 16 + quad * 4 + r;
        int col = n0 + wn * 64 + nt * 16 + l16;
        C[(size_t)row * N + col] = acc[mt][nt][r];
      }
}

// ---------------- GEMM 256x256 (R16-verified): barrier-minimal K-tile ----------------
// (unchanged from R16: stage-first, no intra-tile barriers, one vmcnt(0)+
// barrier per tile; RoPE-pair rtab epilogue; V-transpose repack.)
__global__ __launch_bounds__(512, 2) void gemm256_k(const u16* __restrict__ A,
                                                    const u16* __restrict__ Bt,
                                                    u16* __restrict__ C,
                                                    const float2* __restrict__ rtab,
                                                    int N, int K) {
  __shared__ u16 SM[65536];  // 128 KiB: K-loop Al|Bl, then V-transpose buffer
  u16* const AlB = SM;           // [c][half][8192]: c*16384 + half*8192
  u16* const BlB = SM + 32768;
  const int TN = N >> 8;
  int flat = blockIdx.x;
  const int cpx = gridDim.x >> 3;  // grid % 8 == 0 guaranteed by launch config
  flat = (flat & 7) * cpx + (flat >> 3);
  const int m0 = (flat / TN) << 8, n0 = (flat % TN) << 8;
  const int t = threadIdx.x, w = t >> 6, lane = t & 63;
  const int quad = lane >> 4, l16 = lane & 15;
  const int wm = w >> 2, wn = w & 3;
  const int sr = t >> 3, sl = t & 7;  // staging: row-in-round, lds slot
  floatx4 acc[2][2][4][2] = {};
  const int NKT = K >> 6;

  const int ra_l = wm * 64 + l16;  // + mt*16 ; A row within 128-half
  const int rb_l = wn * 16 + l16;  // + nt*64 ; B row within 128-half (RoPE-pair remap)

  // prologue: stage kt0 into buf0 (A0,B0,B1,A1), full drain once
#pragma unroll
  for (int round = 0; round < 2; round++) {
    int r = round * 64 + sr;
    int so = (sl ^ (r & 7)) << 3;
    gl2lds16(A + (size_t)(m0 + r) * K + so, AlB + round * 4096 + t * 8);
    gl2lds16(Bt + (size_t)(n0 + r) * K + so, BlB + round * 4096 + t * 8);
    gl2lds16(Bt + (size_t)(n0 + 128 + r) * K + so, BlB + 8192 + round * 4096 + t * 8);
    gl2lds16(A + (size_t)(m0 + 128 + r) * K + so, AlB + 8192 + round * 4096 + t * 8);
  }
  asm volatile("s_waitcnt vmcnt(0)" ::: "memory");
  __builtin_amdgcn_s_barrier();

  short8 af[4][2];     // current A-half fragments (reused by 2 quadrants)
  short8 bf[2][2][2];  // [nh][nt][ks] both B-half fragments

  for (int kt = 0; kt < NKT; kt++) {
    const int c = kt & 1;
    const u16* Ab = AlB + c * 16384;
    const u16* Bb = BlB + c * 16384;
    u16* An = AlB + (c ^ 1) * 16384;
    u16* Bn = BlB + (c ^ 1) * 16384;
    // ---- stage kt+1 (8 DMAs) FIRST: maximal in-flight time before tile-end wait ----
    if (kt + 1 < NKT) {
      const int k1 = (kt + 1) << 6;
#pragma unroll
      for (int round = 0; round < 2; round++) {
        int r = round * 64 + sr;
        int so = (sl ^ (r & 7)) << 3;
        gl2lds16(A + (size_t)(m0 + r) * K + k1 + so, An + round * 4096 + t * 8);
        gl2lds16(Bt + (size_t)(n0 + r) * K + k1 + so, Bn + round * 4096 + t * 8);
        gl2lds16(Bt + (size_t)(n0 + 128 + r) * K + k1 + so, Bn + 8192 + round * 4096 + t * 8);
        gl2lds16(A + (size_t)(m0 + 128 + r) * K + k1 + so, An + 8192 + round * 4096 + t * 8);
      }
    }
    // ---- full tile: reads + MFMAs, NO intra-tile barriers ----
    __builtin_amdgcn_s_setprio(1);
    // B0 + A0
#pragma unroll
    for (int nt = 0; nt < 2; nt++) {
      int rb = rb_l + nt * 64;
      const u16* base = Bb + rb * 64;
#pragma unroll
      for (int ks = 0; ks < 2; ks++)
        bf[0][nt][ks] = *(const short8*)(base + (((ks * 4 + quad) ^ (rb & 7)) << 3));
    }
#pragma unroll
    for (int mt = 0; mt < 4; mt++) {
      int ra = ra_l + mt * 16;
      const u16* base = Ab + ra * 64;
#pragma unroll
      for (int ks = 0; ks < 2; ks++)
        af[mt][ks] = *(const short8*)(base + (((ks * 4 + quad) ^ (ra & 7)) << 3));
    }
    // q00
#pragma unroll
    for (int mt = 0; mt < 4; mt++)
#pragma unroll
      for (int nt = 0; nt < 2; nt++)
#pragma unroll
        for (int ks = 0; ks < 2; ks++)
          acc[0][0][mt][nt] =
              __builtin_amdgcn_mfma_f32_16x16x32_bf16(af[mt][ks], bf[0][nt][ks], acc[0][0][mt][nt], 0, 0, 0);
    // B1
#pragma unroll
    for (int nt = 0; nt < 2; nt++) {
      int rb = rb_l + nt * 64;
      const u16* base = Bb + 8192 + rb * 64;
#pragma unroll
      for (int ks = 0; ks < 2; ks++)
        bf[1][nt][ks] = *(const short8*)(base + (((ks * 4 + quad) ^ (rb & 7)) << 3));
    }
    // q01
#pragma unroll
    for (int mt = 0; mt < 4; mt++)
#pragma unroll
      for (int nt = 0; nt < 2; nt++)
#pragma unroll
        for (int ks = 0; ks < 2; ks++)
          acc[0][1][mt][nt] =
              __builtin_amdgcn_mfma_f32_16x16x32_bf16(af[mt][ks], bf[1][nt][ks], acc[0][1][mt][nt], 0, 0, 0);
    // A1
#pragma unroll
    for (int mt = 0; mt < 4; mt++) {
      int ra = ra_l + mt * 16;
      const u16* base = Ab + 8192 + ra * 64;
#pragma unroll
      for (int ks = 0; ks < 2; ks++)
        af[mt][ks] = *(const short8*)(base + (((ks * 4 + quad) ^ (ra & 7)) << 3));
    }
    // q11
#pragma unroll
    for (int mt = 0; mt < 4; mt++)
#pragma unroll
      for (int nt = 0; nt < 2; nt++)
#pragma unroll
        for (int ks = 0; ks < 2; ks++)
          acc[1][1][mt][nt] =
              __builtin_amdgcn_mfma_f32_16x16x32_bf16(af[mt][ks], bf[1][nt][ks], acc[1][1][mt][nt], 0, 0, 0);
    // q10
#pragma unroll
    for (int mt = 0; mt < 4; mt++)
#pragma unroll
      for (int nt = 0; nt < 2; nt++)
#pragma unroll
        for (int ks = 0; ks < 2; ks++)
          acc[1][0][mt][nt] =
              __builtin_amdgcn_mfma_f32_16x16x32_bf16(af[mt][ks], bf[0][nt][ks], acc[1][0][mt][nt], 0, 0, 0);
    __builtin_amdgcn_s_setprio(0);
    // ---- tile-end: retire own stages, then block-wide sync (RAW+WAR) ----
    asm volatile("s_waitcnt vmcnt(0)" ::: "memory");
    __builtin_amdgcn_s_barrier();
  }
  if (n0 < 2560) {
    // ---- epilogue: RoPE from table (Q/K tiles) + bf16 write ----
    const int dloc = wn * 16 + l16;
#pragma unroll
    for (int mh = 0; mh < 2; mh++)
#pragma unroll
      for (int mt = 0; mt < 4; mt++)
#pragma unroll
        for (int r = 0; r < 4; r++) {
          int row = m0 + mh * 128 + wm * 64 + mt * 16 + quad * 4 + r;
          float2 cs = rtab[(row & (S_LEN - 1)) * 64 + dloc];
#pragma unroll
          for (int nh = 0; nh < 2; nh++) {
            float a0 = acc[mh][nh][mt][0][r], a1 = acc[mh][nh][mt][1][r];
            float o0 = a0 * cs.x - a1 * cs.y;
            float o1 = a1 * cs.x + a0 * cs.y;
            int colb = n0 + nh * 128 + wn * 16 + l16;
            C[(size_t)row * N + colb]      = f2bf(o0);
            C[(size_t)row * N + colb + 64] = f2bf(o1);
          }
        }
  } else {
    // ---- epilogue: V-tiles -> transposed repack into QKV's V stripe ----
    const int bbv = m0 >> 11, m0loc = m0 & 2047;
    const int kvbase = (n0 - 2560) >> 7;
    // scatter acc -> SM[lcol][lrow ^ ((lcol&15)<<3)] (b64: 4 r-values per store)
#pragma unroll
    for (int mh = 0; mh < 2; mh++)
#pragma unroll
      for (int nh = 0; nh < 2; nh++)
#pragma unroll
        for (int mt = 0; mt < 4; mt++)
#pragma unroll
          for (int pair = 0; pair < 2; pair++) {
            int lrow = mh * 128 + wm * 64 + mt * 16 + quad * 4;
            int lcol = nh * 128 + wn * 16 + l16 + pair * 64;
            short4v v4 = { (short)f2bf(acc[mh][nh][mt][pair][0]),
                           (short)f2bf(acc[mh][nh][mt][pair][1]),
                           (short)f2bf(acc[mh][nh][mt][pair][2]),
                           (short)f2bf(acc[mh][nh][mt][pair][3]) };
            *(short4v*)(SM + lcol * 256 + (lrow ^ ((lcol & 15) << 3))) = v4;
          }
    asm volatile("s_waitcnt lgkmcnt(0)" ::: "memory");
    __builtin_amdgcn_s_barrier();
    // gather rows of V^T (contiguous keys) -> coalesced global stores
#pragma unroll
    for (int it = 0; it < 16; it++) {
      int u = it * 512 + t;
      int key0 = (u & 31) * 8, lcol = u >> 5;
      short8 v = *(const short8*)(SM + lcol * 256 + (key0 ^ ((lcol & 15) << 3)));
      int d = lcol & 127, kvh = kvbase + (lcol >> 7);
      int key = m0loc + key0;
      *(short8*)(C + (size_t)(bbv * 2048 + kvh * 512 + d * 4 + (key >> 9)) * N + 2560 + (key & 511)) = v;
    }
  }
}

// ---------------- Flash attention, causal GQA (unchanged from R12/R13) ----------------
// NOTE: deliberately NOT converted to the barrier-minimal form -- its per-iter
// compute (~400cy) is shorter than DMA latency, so the counted vmcnt(8)
// (waits loads issued a FULL iteration earlier) gives more in-flight time
// than a tile-end vmcnt(0) would.
__global__ __launch_bounds__(256) void attn_k(const u16* __restrict__ qkv,
                                              u16* __restrict__ ctx) {
  __shared__ u16 Kl[2][64 * 128];      // 2 x 16384 B, [pos][d] swizzled, rows kperm'd
  __shared__ u16 Vl[2][128 * 64];      // 2 x 16384 B, [d][key] swizzled
  const int f = blockIdx.x;
  const int p = f >> 5;
  const int hb = f & 31;
  const int h = hb & 15, bb = hb >> 4;
  const int kvh = h >> 2;
  const int t = threadIdx.x, w = t >> 6, lane = t & 63;
  const int quad = lane >> 4, l16 = lane & 15;
  const int sx = l16 & 7;              // read-side swizzle key
  const int kslot = lane & 15;
  const int vd0 = w * 32 + (lane >> 3);
  const int vslot = lane & 7;
  const int grow0 = (w & 1) * 4 + (w >> 1) * 32 + quad;
  const size_t rowbase = (size_t)bb * S_LEN;
  const u16* Kg0 = qkv + rowbase * NQKV + 2048 + kvh * 128;
  const u16* Vg0 = qkv + (rowbase + kvh * 512) * NQKV + 2560;  // repacked V stripe base
  const float c2 = 0.12751744f;  // (1/sqrt(128)) * log2(e)
  short8 onesf = {16256, 16256, 16256, 16256, 16256, 16256, 16256, 16256};  // bf16 1.0 x8

  for (int phase = 0; phase < 2; phase++) {
    const int qt = phase ? p : 31 - p;  // q-tile index; qt+1 k-iters
    const int rw = qt * 64 + w * 16;    // this wave's first q-row
    const int qrow = rw + l16;          // this lane's q-row (swapped layout: col=q)

    short8 qf[4];
#pragma unroll
    for (int ks = 0; ks < 4; ks++)
      qf[ks] = *(const short8*)(qkv + (rowbase + rw + l16) * NQKV + h * 128 + ks * 32 + quad * 8);

    floatx4 acc[8] = {};
    floatx4 accl = {0.f, 0.f, 0.f, 0.f};

    __syncthreads();  // cross-phase WAR: protect buf0 from previous phase's reads
    // prologue DMA: kb=0 -> buffer 0
    {
#pragma unroll
      for (int ii = 0; ii < 4; ii++) {
        int p7 = (quad + 4 * ii) & 7;  // (position)&7 for the slot swizzle
        int grow = grow0 + 8 * ii;     // permuted global key row
        gl2lds16(Kg0 + (size_t)grow * NQKV + ((kslot ^ p7) * 8),
                 &Kl[0][0] + w * 2048 + ii * 512 + lane * 8);
      }
#pragma unroll
      for (int ii = 0; ii < 4; ii++) {
        int d = vd0 + ii * 8;
        int s8 = (vslot ^ (d & 7)) * 8;
        gl2lds16(Vg0 + (size_t)(d * 4) * NQKV + s8,  // kb=0
                 &Vl[0][0] + w * 2048 + ii * 512 + lane * 8);
      }
    }

    for (int kb = 0; kb <= qt; kb++) {
      const int cur = kb & 1;
      __builtin_amdgcn_s_barrier();  // WAR: all waves done reading buf[cur^1]
      if (kb < qt) {    // prefetch kb+1 into the other buffer
        const int kn = kb + 1;
        const u16* Kg = Kg0 + (size_t)kn * 64 * NQKV;
        u16* KlN = &Kl[cur ^ 1][0];
        u16* VlN = &Vl[cur ^ 1][0];
#pragma unroll
        for (int ii = 0; ii < 4; ii++) {
          int p7 = (quad + 4 * ii) & 7;
          int grow = grow0 + 8 * ii;
          gl2lds16(Kg + (size_t)grow * NQKV + ((kslot ^ p7) * 8),
                   KlN + w * 2048 + ii * 512 + lane * 8);
        }
#pragma unroll
        for (int ii = 0; ii < 4; ii++) {
          int d = vd0 + ii * 8;
          int s8 = (vslot ^ (d & 7)) * 8;
          gl2lds16(Vg0 + (size_t)(d * 4 + (kn >> 3)) * NQKV + (kn & 7) * 64 + s8,
                   VlN + w * 2048 + ii * 512 + lane * 8);
        }
        asm volatile("s_waitcnt vmcnt(8)" ::: "memory");  // buf[cur]'s 8 loads done
      } else {
        asm volatile("s_waitcnt vmcnt(0)" ::: "memory");  // last iter: full drain
      }
      __builtin_amdgcn_s_barrier();  // RAW: all waves' buf[cur] loads landed
      const u16* KlB = &Kl[cur][0];
      const u16* VlB = &Vl[cur][0];

      // ---- QK^T (swapped: A=K, B=Q -> lane holds S[pos=quad*4+r][q=l16]) ----
      floatx4 sc[4];
      __builtin_amdgcn_s_setprio(1);
#pragma unroll
      for (int nt = 0; nt < 4; nt++) {
        const u16* Krow = KlB + (nt * 16 + l16) * 128;
        short8 kf[4];
#pragma unroll
        for (int ks = 0; ks < 4; ks++)
          kf[ks] = *(const short8*)(Krow + (((ks * 4 + quad) ^ sx) * 8));
        floatx4 s = {0.f, 0.f, 0.f, 0.f};
#pragma unroll
        for (int ks = 0; ks < 4; ks++) s = __builtin_amdgcn_mfma_f32_16x16x32_bf16(kf[ks], qf[ks], s, 0, 0, 0);
        sc[nt] = s;
      }
      __builtin_amdgcn_s_setprio(0);
      // ---- P = exp2(score*c2), causal mask, trunc-pack DIRECTLY into A-frags ----
      const bool diag = (kb == qt);
      uint32_t pw[8];
#pragma unroll
      for (int nt = 0; nt < 4; nt++) {
        uint32_t w0 = 0, w1 = 0;
#pragma unroll
        for (int r = 0; r < 4; r++) {
          float e = EXP2F(sc[nt][r] * c2);
          if (diag) {
            int keyg = kb * 64 + quad * 8 + (nt & 1) * 4 + (nt >> 1) * 32 + r;
            if (keyg > qrow) e = 0.f;
          }
          uint32_t b = __float_as_uint(e) >> 16;
          if (r == 0) w0 = b;
          else if (r == 1) w0 |= b << 16;
          else if (r == 2) w1 = b;
          else w1 |= b << 16;
        }
        pw[nt * 2] = w0;
        pw[nt * 2 + 1] = w1;
      }
      union { short8 v; uint32_t u[4]; } pu0, pu1;
      pu0.u[0] = pw[0]; pu0.u[1] = pw[1]; pu0.u[2] = pw[2]; pu0.u[3] = pw[3];
      pu1.u[0] = pw[4]; pu1.u[1] = pw[5]; pu1.u[2] = pw[6]; pu1.u[3] = pw[7];
      const short8 pf0 = pu0.v, pf1 = pu1.v;  // PV A-frags, keys 0-31 / 32-63

      // ---- PV (+ ones-column row-sum into accl) ----
      __builtin_amdgcn_s_setprio(1);
      accl = __builtin_amdgcn_mfma_f32_16x16x32_bf16(pf0, onesf, accl, 0, 0, 0);
      accl = __builtin_amdgcn_mfma_f32_16x16x32_bf16(pf1, onesf, accl, 0, 0, 0);
#pragma unroll
      for (int nto = 0; nto < 8; nto++) {
        const u16* Vrow = VlB + (nto * 16 + l16) * 64;
        short8 vf0 = *(const short8*)(Vrow + ((quad ^ sx) * 8));
        short8 vf1 = *(const short8*)(Vrow + (((quad + 4) ^ sx) * 8));
        acc[nto] = __builtin_amdgcn_mfma_f32_16x16x32_bf16(pf0, vf0, acc[nto], 0, 0, 0);
        acc[nto] = __builtin_amdgcn_mfma_f32_16x16x32_bf16(pf1, vf1, acc[nto], 0, 0, 0);
      }
      __builtin_amdgcn_s_setprio(0);
    }
    // ---- epilogue for this q-tile (lane holds O[q=quad*4+r][d=l16]) ----
#pragma unroll
    for (int r = 0; r < 4; r++) {
      float inv = 1.0f / accl[r];
      int rowg = rw + quad * 4 + r;
#pragma unroll
      for (int nto = 0; nto < 8; nto++) {
        int col = h * 128 + nto * 16 + l16;
        ctx[(rowbase + rowg) * 2048 + col] = f2bf(acc[nto][r] * inv);
      }
    }
  }
}

extern "C" void kernel_launch(void* const* d_in, const int* in_sizes, int n_in,
                              void* d_out, int out_size, void* d_ws, size_t ws_size,
                              hipStream_t stream) {
  const float* x  = (const float*)d_in[0];
  const int* pos  = (const int*)d_in[1];
  const float* Wq = (const float*)d_in[2];
  const float* Wk = (const float*)d_in[3];
  const float* Wv = (const float*)d_in[4];
  const float* Wo = (const float*)d_in[5];
  float* out = (float*)d_out;
  char* ws = (char*)d_ws;
  // ws layout (bf16): Xb[4096][2048] | WT[3072][2048] | WoT[2048][2048] | QKV[4096][3072] | CTX[4096][2048]
  u16* Xb  = (u16*)(ws);
  u16* WT  = (u16*)(ws + 16777216);
  u16* WoT = (u16*)(ws + 29360128);
  u16* QKV = (u16*)(ws + 37748736);
  u16* CTX = (u16*)(ws + 62914560);
  // rtab aliases CTX start (1 MB): written by prep_k, read by gemm256_k,
  // then CTX is overwritten by attn_k (stream-ordered, safe).
  float2* rtab = (float2*)(ws + 62914560);

  // prep: 8192 cast + 5120 transpose + 512 rtab blocks
  hipLaunchKernelGGL(prep_k, dim3(13824), dim3(256), 0, stream, x, Xb, Wq, Wk, Wv, Wo, WT, WoT, pos, rtab);

  // QKV projection + fused RoPE + fused V-repack: grid 192 (192%8==0)
  hipLaunchKernelGGL(gemm256_k, dim3(192), dim3(512), 0, stream, Xb, WT, QKV, rtab, 3072, 2048);
  hipLaunchKernelGGL(attn_k, dim3(512), dim3(256), 0, stream, QKV, CTX);
  // Wo projection: 4096x2048x2048, grid 512 (512%8==0)
  hipLaunchKernelGGL(gemm128_k, dim3(512), dim3(256), 0, stream, CTX, WoT, out, 4096, 2048, 2048);
}